// Round 3
// baseline (3564.244 us; speedup 1.0000x reference)
//
#include <hip/hip_runtime.h>

// DCNv3 forward, FP32 I/O (dataset is float32 — round-1/2 NaN was fp32 words
// misread as bf16 pairs; threshold analysis showed no bf16 eps-floor).
// N=8, H=W=64, C=256, G=16, GC=16, K=3, P=9, PAD=DIL=STR=1. L = 32768.
//
// Structure:
//   k_inproj : xp[l,c] = x[l,:] . in_w[c,:] + in_b[c]  -> ws (fp32, 33.5 MB)
//   k_main   : per pixel: dwconv3x3 + LN + GELU -> offset/mask heads ->
//              softmax -> bilinear deformable gather from xp -> out-proj.
//              offsets/masks live purely in LDS (never materialized).

#define LL 32768
#define CC 256

// dot of 256-float LDS row with an fp32 weight row (float4 loads)
__device__ __forceinline__ float dot256f(const float* a, const float* wrow) {
    const float4* w4 = (const float4*)wrow;
    float s = 0.f;
#pragma unroll 16
    for (int i = 0; i < 64; ++i) {
        float4 u = w4[i];
        const float* ap = a + i * 4;
        s += ap[0] * u.x + ap[1] * u.y + ap[2] * u.z + ap[3] * u.w;
    }
    return s;
}

// ---------------- kernel 1: input projection ------------------------------
__global__ __launch_bounds__(256) void k_inproj(
    const float* __restrict__ x, const float* __restrict__ in_w,
    const float* __restrict__ in_b, float* __restrict__ xp) {
    int l = blockIdx.x;
    int t = threadIdx.x;
    __shared__ float xa[256];
    xa[t] = x[l * CC + t];
    __syncthreads();
    xp[l * CC + t] = dot256f(xa, in_w + t * CC) + in_b[t];
}

// ---------------- kernel 2: everything else, per pixel --------------------
__device__ __forceinline__ float fetch_px(const float* base, int yy, int xx) {
    // base points at xp[n, 0, 0, ch]; pixel stride CC; zeros outside 64x64
    if (xx < 0 || xx >= 64 || yy < 0 || yy >= 64) return 0.f;
    return base[(yy * 64 + xx) * CC];
}

__global__ __launch_bounds__(256) void k_main(
    const float* __restrict__ x, const float* __restrict__ xp,
    const float* __restrict__ dw_w, const float* __restrict__ dw_b,
    const float* __restrict__ ln_g, const float* __restrict__ ln_b,
    const float* __restrict__ off_w, const float* __restrict__ off_b,
    const float* __restrict__ mask_w, const float* __restrict__ mask_b,
    const float* __restrict__ out_w, const float* __restrict__ out_b,
    float* __restrict__ out) {
    int l = blockIdx.x;
    int t = threadIdx.x;
    int w = l & 63, h = (l >> 6) & 63, n = l >> 12;

    __shared__ float x1[256];
    __shared__ float red[256];
    __shared__ float offs[288];
    __shared__ float ms[144];
    __shared__ float row[256];

    // --- depthwise 3x3 conv (cross-correlation), channel t ---
    float acc = dw_b[t];
#pragma unroll
    for (int kh = 0; kh < 3; ++kh) {
        int hh = h + kh - 1;
        if (hh < 0 || hh >= 64) continue;
#pragma unroll
        for (int kw = 0; kw < 3; ++kw) {
            int ww = w + kw - 1;
            if (ww < 0 || ww >= 64) continue;
            acc += x[(((n * 64 + hh) * 64) + ww) * CC + t] * dw_w[t * 9 + kh * 3 + kw];
        }
    }

    // --- LayerNorm over channels ---
    red[t] = acc;
    __syncthreads();
    for (int s = 128; s > 0; s >>= 1) {
        if (t < s) red[t] += red[t + s];
        __syncthreads();
    }
    float mean = red[0] * (1.0f / 256.0f);
    __syncthreads();
    float d = acc - mean;
    red[t] = d * d;
    __syncthreads();
    for (int s = 128; s > 0; s >>= 1) {
        if (t < s) red[t] += red[t + s];
        __syncthreads();
    }
    float var = red[0] * (1.0f / 256.0f);
    float xn = d * rsqrtf(var + 1e-6f) * ln_g[t] + ln_b[t];
    // exact GELU
    x1[t] = 0.5f * xn * (1.0f + erff(xn * 0.70710678118654752f));
    __syncthreads();

    // --- offset head (288) and mask head (144) ---
    offs[t] = dot256f(x1, off_w + t * CC) + off_b[t];
    if (t < 32) {
        int j = 256 + t;
        offs[j] = dot256f(x1, off_w + j * CC) + off_b[j];
    }
    if (t < 144) {
        ms[t] = dot256f(x1, mask_w + t * CC) + mask_b[t];
    }
    __syncthreads();

    // --- softmax over P=9 per group (in place) ---
    if (t < 16) {
        int g = t;
        float mx = -1e30f;
#pragma unroll
        for (int p = 0; p < 9; ++p) mx = fmaxf(mx, ms[g * 9 + p]);
        float s = 0.f;
        float e[9];
#pragma unroll
        for (int p = 0; p < 9; ++p) { e[p] = expf(ms[g * 9 + p] - mx); s += e[p]; }
        float inv = 1.0f / s;
#pragma unroll
        for (int p = 0; p < 9; ++p) ms[g * 9 + p] = e[p] * inv;
    }
    __syncthreads();

    // --- deformable bilinear gather; thread t = g*16 + c' ---
    int g = t >> 4;
    const float* base = xp + (size_t)n * 64 * 64 * CC + t;
    float acc2 = 0.f;
#pragma unroll
    for (int p = 0; p < 9; ++p) {
        float ox = offs[g * 18 + p * 2 + 0];
        float oy = offs[g * 18 + p * 2 + 1];
        // unpadded coords; zeros padding == bounds check on 64x64 image
        float ax = (float)(w + (p / 3) - 1) + ox;
        float ay = (float)(h + (p % 3) - 1) + oy;
        float x0f = floorf(ax), y0f = floorf(ay);
        int x0 = (int)x0f, y0 = (int)y0f;
        float tx = ax - x0f, ty = ay - y0f;
        float v00 = fetch_px(base, y0, x0);
        float v01 = fetch_px(base, y0, x0 + 1);
        float v10 = fetch_px(base, y0 + 1, x0);
        float v11 = fetch_px(base, y0 + 1, x0 + 1);
        float bl = (v00 * (1.f - tx) + v01 * tx) * (1.f - ty) +
                   (v10 * (1.f - tx) + v11 * tx) * ty;
        acc2 += ms[g * 9 + p] * bl;
    }
    row[t] = acc2;
    __syncthreads();

    // --- output projection ---
    out[l * CC + t] = dot256f(row, out_w + t * CC) + out_b[t];
}

extern "C" void kernel_launch(void* const* d_in, const int* in_sizes, int n_in,
                              void* d_out, int out_size, void* d_ws,
                              size_t ws_size, hipStream_t stream) {
    const float* x      = (const float*)d_in[0];
    const float* dw_w   = (const float*)d_in[1];
    const float* dw_b   = (const float*)d_in[2];
    const float* ln_g   = (const float*)d_in[3];
    const float* ln_b   = (const float*)d_in[4];
    const float* off_w  = (const float*)d_in[5];
    const float* off_b  = (const float*)d_in[6];
    const float* mask_w = (const float*)d_in[7];
    const float* mask_b = (const float*)d_in[8];
    const float* in_w   = (const float*)d_in[9];
    const float* in_b   = (const float*)d_in[10];
    const float* out_w  = (const float*)d_in[11];
    const float* out_b  = (const float*)d_in[12];
    float* out = (float*)d_out;

    float* xp = (float*)d_ws;   // 32768*256*4 = 33.5 MB — entire ws footprint

    dim3 grid(LL), block(256);
    k_inproj<<<grid, block, 0, stream>>>(x, in_w, in_b, xp);
    k_main<<<grid, block, 0, stream>>>(x, xp, dw_w, dw_b, ln_g, ln_b,
                                       off_w, off_b, mask_w, mask_b,
                                       out_w, out_b, out);
}

// Round 4
// 522.318 us; speedup vs baseline: 6.8239x; 6.8239x over previous
//
#include <hip/hip_runtime.h>

// DCNv3 forward, FP32. N=8, H=W=64, C=256, G=16, GC=16, K=3, P=9. L=32768.
//
// Fast path (ws >= 123.7 MB):
//   k_dwln    : dwconv3x3 + LN + GELU -> x1
//   k_gemm256 : xp     = x    @ in_w^T   + in_b    (N=256)
//   k_gemm256 : off    = x1   @ off_w^T  + off_b   (N=288)
//   k_gemm256 : logits = x1   @ mask_w^T + mask_b  (N=144)
//   k_gather  : softmax(logits) + bilinear gather from xp -> rows (overlays x1)
//   k_gemm256 : out    = rows @ out_w^T  + out_b   (N=256)
// Fallback path (round-3 kernels, ws >= 33.5 MB) if ws is small.

#define LL 32768
#define CC 256

// ------------------------- tiled fp32 GEMM --------------------------------
// C[m][n] = dot(A[m][:256], W[n][:256]) + bias[n]; M=32768 (div 64), runtime N.
// 64x64 tile, K-chunks of 16, 4x4 accum per thread, 256 threads.
__global__ __launch_bounds__(256) void k_gemm256(
    const float* __restrict__ A, const float* __restrict__ W,
    const float* __restrict__ bias, float* __restrict__ C, int Nout) {
    int mb = blockIdx.x * 64;
    int nb = blockIdx.y * 64;
    int t = threadIdx.x;
    int tx = t & 15, ty = t >> 4;

    __shared__ float As[16][68];   // [kk][m], pad 68: staging writes <=2-way
    __shared__ float Ws[16][68];   // [kk][n]

    float acc[4][4];
#pragma unroll
    for (int i = 0; i < 4; ++i)
#pragma unroll
        for (int j = 0; j < 4; ++j) acc[i][j] = 0.f;

    int sm = t >> 2;           // staging row 0..63
    int kq = (t & 3) * 4;      // 0,4,8,12
    const float* Arow = A + (size_t)(mb + sm) * CC + kq;
    const float* Wrow = W + (size_t)(nb + sm) * CC + kq;
    bool wvalid = (nb + sm) < Nout;

    for (int kc = 0; kc < 256; kc += 16) {
        float4 av = *(const float4*)(Arow + kc);
        float4 wv = wvalid ? *(const float4*)(Wrow + kc)
                           : make_float4(0.f, 0.f, 0.f, 0.f);
        As[kq + 0][sm] = av.x; As[kq + 1][sm] = av.y;
        As[kq + 2][sm] = av.z; As[kq + 3][sm] = av.w;
        Ws[kq + 0][sm] = wv.x; Ws[kq + 1][sm] = wv.y;
        Ws[kq + 2][sm] = wv.z; Ws[kq + 3][sm] = wv.w;
        __syncthreads();
#pragma unroll
        for (int kk = 0; kk < 16; ++kk) {
            float4 a = *(const float4*)&As[kk][ty * 4];   // ds_read_b128
            float4 b = *(const float4*)&Ws[kk][tx * 4];   // ds_read_b128
            acc[0][0] += a.x * b.x; acc[0][1] += a.x * b.y;
            acc[0][2] += a.x * b.z; acc[0][3] += a.x * b.w;
            acc[1][0] += a.y * b.x; acc[1][1] += a.y * b.y;
            acc[1][2] += a.y * b.z; acc[1][3] += a.y * b.w;
            acc[2][0] += a.z * b.x; acc[2][1] += a.z * b.y;
            acc[2][2] += a.z * b.z; acc[2][3] += a.z * b.w;
            acc[3][0] += a.w * b.x; acc[3][1] += a.w * b.y;
            acc[3][2] += a.w * b.z; acc[3][3] += a.w * b.w;
        }
        __syncthreads();
    }

    int n0 = nb + tx * 4;
    if (n0 + 4 <= Nout) {      // all our N (256/288/144) end on x4 boundaries
        float4 bv = *(const float4*)&bias[n0];
#pragma unroll
        for (int i = 0; i < 4; ++i) {
            int m = mb + ty * 4 + i;
            float4 o;
            o.x = acc[i][0] + bv.x; o.y = acc[i][1] + bv.y;
            o.z = acc[i][2] + bv.z; o.w = acc[i][3] + bv.w;
            *(float4*)&C[(size_t)m * Nout + n0] = o;
        }
    }
}

// ------------------- dwconv 3x3 + LayerNorm + exact GELU ------------------
__global__ __launch_bounds__(256) void k_dwln(
    const float* __restrict__ x, const float* __restrict__ dw_w,
    const float* __restrict__ dw_b, const float* __restrict__ ln_g,
    const float* __restrict__ ln_b, float* __restrict__ x1) {
    int l = blockIdx.x;
    int t = threadIdx.x;
    int w = l & 63, h = (l >> 6) & 63, n = l >> 12;

    float acc = dw_b[t];
#pragma unroll
    for (int kh = 0; kh < 3; ++kh) {
        int hh = h + kh - 1;
        if (hh < 0 || hh >= 64) continue;
#pragma unroll
        for (int kw = 0; kw < 3; ++kw) {
            int ww = w + kw - 1;
            if (ww < 0 || ww >= 64) continue;
            acc += x[(((n * 64 + hh) * 64) + ww) * CC + t] * dw_w[t * 9 + kh * 3 + kw];
        }
    }
    __shared__ float red[256];
    red[t] = acc;
    __syncthreads();
    for (int s = 128; s > 0; s >>= 1) {
        if (t < s) red[t] += red[t + s];
        __syncthreads();
    }
    float mean = red[0] * (1.0f / 256.0f);
    __syncthreads();
    float d = acc - mean;
    red[t] = d * d;
    __syncthreads();
    for (int s = 128; s > 0; s >>= 1) {
        if (t < s) red[t] += red[t + s];
        __syncthreads();
    }
    float var = red[0] * (1.0f / 256.0f);
    float xn = d * rsqrtf(var + 1e-6f) * ln_g[t] + ln_b[t];
    x1[l * CC + t] = 0.5f * xn * (1.0f + erff(xn * 0.70710678118654752f));
}

// ----------------- softmax + deformable bilinear gather -------------------
__device__ __forceinline__ float fetch_px(const float* base, int yy, int xx) {
    if (xx < 0 || xx >= 64 || yy < 0 || yy >= 64) return 0.f;
    return base[(yy * 64 + xx) * CC];
}

__global__ __launch_bounds__(256) void k_gather(
    const float* __restrict__ xp, const float* __restrict__ off,
    const float* __restrict__ logits, float* __restrict__ rows) {
    int l = blockIdx.x;
    int t = threadIdx.x;
    int w = l & 63, h = (l >> 6) & 63, n = l >> 12;

    __shared__ float offs[288];
    __shared__ float ms[144];
    offs[t] = off[(size_t)l * 288 + t];
    if (t < 32) offs[256 + t] = off[(size_t)l * 288 + 256 + t];
    if (t < 144) ms[t] = logits[(size_t)l * 144 + t];
    __syncthreads();

    if (t < 16) {
        int g = t;
        float mx = -1e30f;
#pragma unroll
        for (int p = 0; p < 9; ++p) mx = fmaxf(mx, ms[g * 9 + p]);
        float s = 0.f, e[9];
#pragma unroll
        for (int p = 0; p < 9; ++p) { e[p] = expf(ms[g * 9 + p] - mx); s += e[p]; }
        float inv = 1.0f / s;
#pragma unroll
        for (int p = 0; p < 9; ++p) ms[g * 9 + p] = e[p] * inv;
    }
    __syncthreads();

    int g = t >> 4;
    const float* base = xp + (size_t)n * 64 * 64 * CC + t;
    float acc = 0.f;
#pragma unroll
    for (int p = 0; p < 9; ++p) {
        float ox = offs[g * 18 + p * 2 + 0];
        float oy = offs[g * 18 + p * 2 + 1];
        float ax = (float)(w + (p / 3) - 1) + ox;
        float ay = (float)(h + (p % 3) - 1) + oy;
        float x0f = floorf(ax), y0f = floorf(ay);
        int x0 = (int)x0f, y0 = (int)y0f;
        float tx = ax - x0f, ty = ay - y0f;
        float v00 = fetch_px(base, y0, x0);
        float v01 = fetch_px(base, y0, x0 + 1);
        float v10 = fetch_px(base, y0 + 1, x0);
        float v11 = fetch_px(base, y0 + 1, x0 + 1);
        float bl = (v00 * (1.f - tx) + v01 * tx) * (1.f - ty) +
                   (v10 * (1.f - tx) + v11 * tx) * ty;
        acc += ms[g * 9 + p] * bl;
    }
    rows[(size_t)l * CC + t] = acc;
}

// ======================= round-3 fallback kernels =========================
__device__ __forceinline__ float dot256f(const float* a, const float* wrow) {
    const float4* w4 = (const float4*)wrow;
    float s = 0.f;
#pragma unroll 16
    for (int i = 0; i < 64; ++i) {
        float4 u = w4[i];
        const float* ap = a + i * 4;
        s += ap[0] * u.x + ap[1] * u.y + ap[2] * u.z + ap[3] * u.w;
    }
    return s;
}

__global__ __launch_bounds__(256) void k_inproj_fb(
    const float* __restrict__ x, const float* __restrict__ in_w,
    const float* __restrict__ in_b, float* __restrict__ xp) {
    int l = blockIdx.x;
    int t = threadIdx.x;
    __shared__ float xa[256];
    xa[t] = x[l * CC + t];
    __syncthreads();
    xp[l * CC + t] = dot256f(xa, in_w + t * CC) + in_b[t];
}

__global__ __launch_bounds__(256) void k_main_fb(
    const float* __restrict__ x, const float* __restrict__ xp,
    const float* __restrict__ dw_w, const float* __restrict__ dw_b,
    const float* __restrict__ ln_g, const float* __restrict__ ln_b,
    const float* __restrict__ off_w, const float* __restrict__ off_b,
    const float* __restrict__ mask_w, const float* __restrict__ mask_b,
    const float* __restrict__ out_w, const float* __restrict__ out_b,
    float* __restrict__ out) {
    int l = blockIdx.x;
    int t = threadIdx.x;
    int w = l & 63, h = (l >> 6) & 63, n = l >> 12;
    __shared__ float x1[256];
    __shared__ float red[256];
    __shared__ float offs[288];
    __shared__ float ms[144];
    __shared__ float row[256];

    float acc = dw_b[t];
#pragma unroll
    for (int kh = 0; kh < 3; ++kh) {
        int hh = h + kh - 1;
        if (hh < 0 || hh >= 64) continue;
#pragma unroll
        for (int kw = 0; kw < 3; ++kw) {
            int ww = w + kw - 1;
            if (ww < 0 || ww >= 64) continue;
            acc += x[(((n * 64 + hh) * 64) + ww) * CC + t] * dw_w[t * 9 + kh * 3 + kw];
        }
    }
    red[t] = acc;
    __syncthreads();
    for (int s = 128; s > 0; s >>= 1) {
        if (t < s) red[t] += red[t + s];
        __syncthreads();
    }
    float mean = red[0] * (1.0f / 256.0f);
    __syncthreads();
    float d = acc - mean;
    red[t] = d * d;
    __syncthreads();
    for (int s = 128; s > 0; s >>= 1) {
        if (t < s) red[t] += red[t + s];
        __syncthreads();
    }
    float var = red[0] * (1.0f / 256.0f);
    float xn = d * rsqrtf(var + 1e-6f) * ln_g[t] + ln_b[t];
    x1[t] = 0.5f * xn * (1.0f + erff(xn * 0.70710678118654752f));
    __syncthreads();

    offs[t] = dot256f(x1, off_w + t * CC) + off_b[t];
    if (t < 32) {
        int j = 256 + t;
        offs[j] = dot256f(x1, off_w + j * CC) + off_b[j];
    }
    if (t < 144) ms[t] = dot256f(x1, mask_w + t * CC) + mask_b[t];
    __syncthreads();

    if (t < 16) {
        int g = t;
        float mx = -1e30f;
#pragma unroll
        for (int p = 0; p < 9; ++p) mx = fmaxf(mx, ms[g * 9 + p]);
        float s = 0.f, e[9];
#pragma unroll
        for (int p = 0; p < 9; ++p) { e[p] = expf(ms[g * 9 + p] - mx); s += e[p]; }
        float inv = 1.0f / s;
#pragma unroll
        for (int p = 0; p < 9; ++p) ms[g * 9 + p] = e[p] * inv;
    }
    __syncthreads();

    int g = t >> 4;
    const float* base = xp + (size_t)n * 64 * 64 * CC + t;
    float acc2 = 0.f;
#pragma unroll
    for (int p = 0; p < 9; ++p) {
        float ox = offs[g * 18 + p * 2 + 0];
        float oy = offs[g * 18 + p * 2 + 1];
        float ax = (float)(w + (p / 3) - 1) + ox;
        float ay = (float)(h + (p % 3) - 1) + oy;
        float x0f = floorf(ax), y0f = floorf(ay);
        int x0 = (int)x0f, y0 = (int)y0f;
        float tx = ax - x0f, ty = ay - y0f;
        float v00 = fetch_px(base, y0, x0);
        float v01 = fetch_px(base, y0, x0 + 1);
        float v10 = fetch_px(base, y0 + 1, x0);
        float v11 = fetch_px(base, y0 + 1, x0 + 1);
        float bl = (v00 * (1.f - tx) + v01 * tx) * (1.f - ty) +
                   (v10 * (1.f - tx) + v11 * tx) * ty;
        acc2 += ms[g * 9 + p] * bl;
    }
    row[t] = acc2;
    __syncthreads();
    out[l * CC + t] = dot256f(row, out_w + t * CC) + out_b[t];
}

// ==========================================================================
extern "C" void kernel_launch(void* const* d_in, const int* in_sizes, int n_in,
                              void* d_out, int out_size, void* d_ws,
                              size_t ws_size, hipStream_t stream) {
    const float* x      = (const float*)d_in[0];
    const float* dw_w   = (const float*)d_in[1];
    const float* dw_b   = (const float*)d_in[2];
    const float* ln_g   = (const float*)d_in[3];
    const float* ln_b   = (const float*)d_in[4];
    const float* off_w  = (const float*)d_in[5];
    const float* off_b  = (const float*)d_in[6];
    const float* mask_w = (const float*)d_in[7];
    const float* mask_b = (const float*)d_in[8];
    const float* in_w   = (const float*)d_in[9];
    const float* in_b   = (const float*)d_in[10];
    const float* out_w  = (const float*)d_in[11];
    const float* out_b  = (const float*)d_in[12];
    float* out = (float*)d_out;

    const size_t szLC  = (size_t)LL * CC * 4;       // 33,554,432
    const size_t szOFF = (size_t)LL * 288 * 4;      // 37,748,736
    const size_t szLOG = (size_t)LL * 144 * 4;      // 18,874,368
    const size_t need  = szLC * 2 + szOFF + szLOG;  // 123,731,968

    if (ws_size >= need) {
        char* p = (char*)d_ws;
        float* x1     = (float*)p; p += szLC;    // later reused as `rows`
        float* xp     = (float*)p; p += szLC;
        float* offv   = (float*)p; p += szOFF;
        float* logits = (float*)p;
        float* rows   = x1;                      // x1 dead after head GEMMs

        dim3 blk(256);
        k_dwln<<<dim3(LL), blk, 0, stream>>>(x, dw_w, dw_b, ln_g, ln_b, x1);
        k_gemm256<<<dim3(LL / 64, 4), blk, 0, stream>>>(x, in_w, in_b, xp, 256);
        k_gemm256<<<dim3(LL / 64, 5), blk, 0, stream>>>(x1, off_w, off_b, offv, 288);
        k_gemm256<<<dim3(LL / 64, 3), blk, 0, stream>>>(x1, mask_w, mask_b, logits, 144);
        k_gather<<<dim3(LL), blk, 0, stream>>>(xp, offv, logits, rows);
        k_gemm256<<<dim3(LL / 64, 4), blk, 0, stream>>>(rows, out_w, out_b, out, 256);
    } else {
        float* xp = (float*)d_ws;
        dim3 blk(256);
        k_inproj_fb<<<dim3(LL), blk, 0, stream>>>(x, in_w, in_b, xp);
        k_main_fb<<<dim3(LL), blk, 0, stream>>>(x, xp, dw_w, dw_b, ln_g, ln_b,
                                                off_w, off_b, mask_w, mask_b,
                                                out_w, out_b, out);
    }
}

// Round 5
// 323.794 us; speedup vs baseline: 11.0078x; 1.6131x over previous
//
#include <hip/hip_runtime.h>

// DCNv3 forward, FP32 I/O. N=8, H=W=64, C=256, G=16, GC=16, K=3, P=9. L=32768.
//
// Round-5: MFMA (bf16 hi/lo split, 3-product) for the 4 GEMMs.
//   k_dwt / k_cvt : weight + activation fp32 -> bf16 hi/lo
//   k_dwln        : dwconv3x3 + LN + GELU (wave per pixel, shfl reduce) -> x1 hi/lo
//   k_mfma_gemm   : C = A @ W^T + b  via v_mfma_f32_16x16x32_bf16,
//                   acc += Ah*Wh + Ah*Wl + Al*Wh  (fp32-grade accuracy)
//   k_gather      : softmax + bilinear gather, float4 (4 ch/thread) -> rows hi/lo
// Fallback: round-4 fp32 path if ws_size < 158.3 MB.

#define LL 32768
#define CC 256

typedef __bf16 bf16;
typedef __bf16 bf16x4 __attribute__((ext_vector_type(4)));
typedef __bf16 bf16x8 __attribute__((ext_vector_type(8)));
typedef float f32x4v __attribute__((ext_vector_type(4)));

// ---------------- fp32 -> bf16 hi/lo conversion (RNE via hw cvt) ----------
__global__ __launch_bounds__(256) void k_cvt(
    const float* __restrict__ s, bf16* __restrict__ hi, bf16* __restrict__ lo,
    int n4) {
    int i = blockIdx.x * 256 + threadIdx.x;
    if (i >= n4) return;
    float4 v = *(const float4*)(s + (size_t)i * 4);
    bf16x4 h, l;
    h[0] = (bf16)v.x; l[0] = (bf16)(v.x - (float)h[0]);
    h[1] = (bf16)v.y; l[1] = (bf16)(v.y - (float)h[1]);
    h[2] = (bf16)v.z; l[2] = (bf16)(v.z - (float)h[2]);
    h[3] = (bf16)v.w; l[3] = (bf16)(v.w - (float)h[3]);
    *(bf16x4*)(hi + (size_t)i * 4) = h;
    *(bf16x4*)(lo + (size_t)i * 4) = l;
}

// dw_w (C,1,3,3) -> dwT[j][c] transposed fp32 for float4 loads
__global__ __launch_bounds__(256) void k_dwt(
    const float* __restrict__ dw_w, float* __restrict__ dwT) {
    int j = blockIdx.x, c = threadIdx.x;
    dwT[j * 256 + c] = dw_w[c * 9 + j];
}

// ---------------- dwconv3x3 + LN + GELU: wave per pixel, 4 ch/thread ------
__global__ __launch_bounds__(256) void k_dwln(
    const float* __restrict__ x, const float* __restrict__ dwT,
    const float* __restrict__ dw_b, const float* __restrict__ ln_g,
    const float* __restrict__ ln_b, bf16* __restrict__ x1h,
    bf16* __restrict__ x1l) {
    int t = threadIdx.x;
    int q = t >> 6, u = t & 63;            // pixel-in-block, lane
    int l = blockIdx.x * 4 + q;
    int w = l & 63, h = (l >> 6) & 63, n = l >> 12;
    int c0 = u * 4;

    float4 acc = *(const float4*)(dw_b + c0);
#pragma unroll
    for (int kh = 0; kh < 3; ++kh) {
        int hh = h + kh - 1;
        if (hh < 0 || hh >= 64) continue;
#pragma unroll
        for (int kw = 0; kw < 3; ++kw) {
            int ww = w + kw - 1;
            if (ww < 0 || ww >= 64) continue;
            float4 xv = *(const float4*)(x + (size_t)(((n * 64 + hh) * 64) + ww) * CC + c0);
            float4 wv = *(const float4*)(dwT + (kh * 3 + kw) * 256 + c0);
            acc.x += xv.x * wv.x; acc.y += xv.y * wv.y;
            acc.z += xv.z * wv.z; acc.w += xv.w * wv.w;
        }
    }
    float s = acc.x + acc.y + acc.z + acc.w;
    float ss = acc.x * acc.x + acc.y * acc.y + acc.z * acc.z + acc.w * acc.w;
#pragma unroll
    for (int d = 1; d < 64; d <<= 1) {
        s += __shfl_xor(s, d);
        ss += __shfl_xor(ss, d);
    }
    float mean = s * (1.0f / 256.0f);
    float var = ss * (1.0f / 256.0f) - mean * mean;
    float rstd = rsqrtf(var + 1e-6f);
    float4 gv = *(const float4*)(ln_g + c0);
    float4 bv = *(const float4*)(ln_b + c0);
    float xn0 = (acc.x - mean) * rstd * gv.x + bv.x;
    float xn1 = (acc.y - mean) * rstd * gv.y + bv.y;
    float xn2 = (acc.z - mean) * rstd * gv.z + bv.z;
    float xn3 = (acc.w - mean) * rstd * gv.w + bv.w;
    float g0 = 0.5f * xn0 * (1.0f + erff(xn0 * 0.70710678118654752f));
    float g1 = 0.5f * xn1 * (1.0f + erff(xn1 * 0.70710678118654752f));
    float g2 = 0.5f * xn2 * (1.0f + erff(xn2 * 0.70710678118654752f));
    float g3 = 0.5f * xn3 * (1.0f + erff(xn3 * 0.70710678118654752f));
    bf16x4 oh, ol;
    oh[0] = (bf16)g0; ol[0] = (bf16)(g0 - (float)oh[0]);
    oh[1] = (bf16)g1; ol[1] = (bf16)(g1 - (float)oh[1]);
    oh[2] = (bf16)g2; ol[2] = (bf16)(g2 - (float)oh[2]);
    oh[3] = (bf16)g3; ol[3] = (bf16)(g3 - (float)oh[3]);
    *(bf16x4*)(x1h + (size_t)l * CC + c0) = oh;
    *(bf16x4*)(x1l + (size_t)l * CC + c0) = ol;
}

// ---------------- MFMA split-bf16 GEMM: C[m][n] = A[m][:].W[n][:] + b -----
// M=32768 (x64 tiles), N covered in 256-blocks (grid.y), K=256.
// Block: 256 thr = 4 waves; wave w computes m-tiles 0..3 x n-tiles 4w..4w+3.
__global__ __launch_bounds__(256) void k_mfma_gemm(
    const bf16* __restrict__ Ah, const bf16* __restrict__ Al,
    const bf16* __restrict__ Wh, const bf16* __restrict__ Wl,
    const float* __restrict__ bias, float* __restrict__ C, int Nout) {
    int mb = blockIdx.x * 64;
    int nb = blockIdx.y * 256;
    int t = threadIdx.x;
    int wave = t >> 6, lane = t & 63;

    __shared__ bf16 sAh[64][32];
    __shared__ bf16 sAl[64][32];
    __shared__ bf16 sWh[256][32];
    __shared__ bf16 sWl[256][32];

    f32x4v acc[4][4];
#pragma unroll
    for (int i = 0; i < 4; ++i)
#pragma unroll
        for (int j = 0; j < 4; ++j) acc[i][j] = (f32x4v){0.f, 0.f, 0.f, 0.f};

    int r = t >> 2, cq = t & 3;     // staging: row r, 8-elem chunk cq
    int fm = lane & 15, fq = lane >> 4;

    for (int kc = 0; kc < 256; kc += 32) {
        // stage A hi/lo (64 rows x 32 k)
        *(uint4*)&sAh[r][cq * 8] =
            *(const uint4*)(Ah + (size_t)(mb + r) * CC + kc + cq * 8);
        *(uint4*)&sAl[r][cq * 8] =
            *(const uint4*)(Al + (size_t)(mb + r) * CC + kc + cq * 8);
        // stage W hi/lo (256 rows x 32 k), zero-pad rows >= Nout
#pragma unroll
        for (int i = 0; i < 4; ++i) {
            int wr = r + 64 * i;
            int wn = nb + wr;
            uint4 vh = {0, 0, 0, 0}, vl = {0, 0, 0, 0};
            if (wn < Nout) {
                vh = *(const uint4*)(Wh + (size_t)wn * CC + kc + cq * 8);
                vl = *(const uint4*)(Wl + (size_t)wn * CC + kc + cq * 8);
            }
            *(uint4*)&sWh[wr][cq * 8] = vh;
            *(uint4*)&sWl[wr][cq * 8] = vl;
        }
        __syncthreads();

        bf16x8 afh[4], afl[4], bfh[4], bfl[4];
#pragma unroll
        for (int i = 0; i < 4; ++i) {
            afh[i] = *(const bf16x8*)&sAh[i * 16 + fm][fq * 8];
            afl[i] = *(const bf16x8*)&sAl[i * 16 + fm][fq * 8];
        }
#pragma unroll
        for (int j = 0; j < 4; ++j) {
            int n0 = wave * 64 + j * 16;
            bfh[j] = *(const bf16x8*)&sWh[n0 + fm][fq * 8];
            bfl[j] = *(const bf16x8*)&sWl[n0 + fm][fq * 8];
        }
#pragma unroll
        for (int i = 0; i < 4; ++i)
#pragma unroll
            for (int j = 0; j < 4; ++j) {
                acc[i][j] = __builtin_amdgcn_mfma_f32_16x16x32_bf16(
                    afh[i], bfh[j], acc[i][j], 0, 0, 0);
                acc[i][j] = __builtin_amdgcn_mfma_f32_16x16x32_bf16(
                    afh[i], bfl[j], acc[i][j], 0, 0, 0);
                acc[i][j] = __builtin_amdgcn_mfma_f32_16x16x32_bf16(
                    afl[i], bfh[j], acc[i][j], 0, 0, 0);
            }
        __syncthreads();
    }

    // epilogue: D[m][n]: m = tile*16 + fq*4 + reg, n = tile*16 + fm
#pragma unroll
    for (int j = 0; j < 4; ++j) {
        int n_g = nb + wave * 64 + j * 16 + fm;
        if (n_g >= Nout) continue;
        float bv = bias[n_g];
#pragma unroll
        for (int i = 0; i < 4; ++i) {
            int m_g = mb + i * 16 + fq * 4;
#pragma unroll
            for (int rg = 0; rg < 4; ++rg)
                C[(size_t)(m_g + rg) * Nout + n_g] = acc[i][j][rg] + bv;
        }
    }
}

// ---------------- softmax + bilinear gather (4 ch/thread) -> rows hi/lo ---
__global__ __launch_bounds__(256) void k_gather(
    const float* __restrict__ xp, const float* __restrict__ off,
    const float* __restrict__ logits, bf16* __restrict__ rh,
    bf16* __restrict__ rl) {
    int t = threadIdx.x;
    int q = t >> 6, u = t & 63;
    int l = blockIdx.x * 4 + q;
    int w = l & 63, h = (l >> 6) & 63, n = l >> 12;

    __shared__ float offs[4][288];
    __shared__ float ms[4][144];
    for (int j = u; j < 288; j += 64) offs[q][j] = off[(size_t)l * 288 + j];
    for (int j = u; j < 144; j += 64) ms[q][j] = logits[(size_t)l * 144 + j];
    __syncthreads();

    if (u < 16) {
        int g = u;
        float mx = -1e30f;
#pragma unroll
        for (int p = 0; p < 9; ++p) mx = fmaxf(mx, ms[q][g * 9 + p]);
        float s = 0.f, e[9];
#pragma unroll
        for (int p = 0; p < 9; ++p) { e[p] = expf(ms[q][g * 9 + p] - mx); s += e[p]; }
        float inv = 1.0f / s;
#pragma unroll
        for (int p = 0; p < 9; ++p) ms[q][g * 9 + p] = e[p] * inv;
    }
    __syncthreads();

    int g = u >> 2;
    int c0 = g * 16 + (u & 3) * 4;
    const float* base = xp + (size_t)n * 4096 * CC + c0;
    float a0 = 0.f, a1 = 0.f, a2 = 0.f, a3 = 0.f;
#pragma unroll
    for (int p = 0; p < 9; ++p) {
        float ox = offs[q][g * 18 + p * 2 + 0];
        float oy = offs[q][g * 18 + p * 2 + 1];
        float ax = (float)(w + (p / 3) - 1) + ox;
        float ay = (float)(h + (p % 3) - 1) + oy;
        float x0f = floorf(ax), y0f = floorf(ay);
        int x0 = (int)x0f, y0 = (int)y0f;
        float tx = ax - x0f, ty = ay - y0f;
        float m = ms[q][g * 9 + p];
        float w00 = m * (1.f - tx) * (1.f - ty);
        float w01 = m * tx * (1.f - ty);
        float w10 = m * (1.f - tx) * ty;
        float w11 = m * tx * ty;
#pragma unroll
        for (int cr = 0; cr < 4; ++cr) {
            int xx = x0 + (cr & 1), yy = y0 + (cr >> 1);
            float wt = (cr == 0) ? w00 : (cr == 1) ? w01 : (cr == 2) ? w10 : w11;
            if (xx >= 0 && xx < 64 && yy >= 0 && yy < 64) {
                float4 v = *(const float4*)(base + (size_t)(yy * 64 + xx) * CC);
                a0 += wt * v.x; a1 += wt * v.y; a2 += wt * v.z; a3 += wt * v.w;
            }
        }
    }
    bf16x4 oh, ol;
    oh[0] = (bf16)a0; ol[0] = (bf16)(a0 - (float)oh[0]);
    oh[1] = (bf16)a1; ol[1] = (bf16)(a1 - (float)oh[1]);
    oh[2] = (bf16)a2; ol[2] = (bf16)(a2 - (float)oh[2]);
    oh[3] = (bf16)a3; ol[3] = (bf16)(a3 - (float)oh[3]);
    *(bf16x4*)(rh + (size_t)l * CC + c0) = oh;
    *(bf16x4*)(rl + (size_t)l * CC + c0) = ol;
}

// ======================= round-4 fallback (fp32) ==========================
__global__ __launch_bounds__(256) void k_gemm256_fb(
    const float* __restrict__ A, const float* __restrict__ W,
    const float* __restrict__ bias, float* __restrict__ C, int Nout) {
    int mb = blockIdx.x * 64;
    int nb = blockIdx.y * 64;
    int t = threadIdx.x;
    int tx = t & 15, ty = t >> 4;
    __shared__ float As[16][68];
    __shared__ float Ws[16][68];
    float acc[4][4];
#pragma unroll
    for (int i = 0; i < 4; ++i)
#pragma unroll
        for (int j = 0; j < 4; ++j) acc[i][j] = 0.f;
    int sm = t >> 2;
    int kq = (t & 3) * 4;
    const float* Arow = A + (size_t)(mb + sm) * CC + kq;
    const float* Wrow = W + (size_t)(nb + sm) * CC + kq;
    bool wvalid = (nb + sm) < Nout;
    for (int kc = 0; kc < 256; kc += 16) {
        float4 av = *(const float4*)(Arow + kc);
        float4 wv = wvalid ? *(const float4*)(Wrow + kc)
                           : make_float4(0.f, 0.f, 0.f, 0.f);
        As[kq + 0][sm] = av.x; As[kq + 1][sm] = av.y;
        As[kq + 2][sm] = av.z; As[kq + 3][sm] = av.w;
        Ws[kq + 0][sm] = wv.x; Ws[kq + 1][sm] = wv.y;
        Ws[kq + 2][sm] = wv.z; Ws[kq + 3][sm] = wv.w;
        __syncthreads();
#pragma unroll
        for (int kk = 0; kk < 16; ++kk) {
            float4 a = *(const float4*)&As[kk][ty * 4];
            float4 b = *(const float4*)&Ws[kk][tx * 4];
            acc[0][0] += a.x * b.x; acc[0][1] += a.x * b.y;
            acc[0][2] += a.x * b.z; acc[0][3] += a.x * b.w;
            acc[1][0] += a.y * b.x; acc[1][1] += a.y * b.y;
            acc[1][2] += a.y * b.z; acc[1][3] += a.y * b.w;
            acc[2][0] += a.z * b.x; acc[2][1] += a.z * b.y;
            acc[2][2] += a.z * b.z; acc[2][3] += a.z * b.w;
            acc[3][0] += a.w * b.x; acc[3][1] += a.w * b.y;
            acc[3][2] += a.w * b.z; acc[3][3] += a.w * b.w;
        }
        __syncthreads();
    }
    int n0 = nb + tx * 4;
    if (n0 + 4 <= Nout) {
        float4 bv = *(const float4*)&bias[n0];
#pragma unroll
        for (int i = 0; i < 4; ++i) {
            int m = mb + ty * 4 + i;
            float4 o;
            o.x = acc[i][0] + bv.x; o.y = acc[i][1] + bv.y;
            o.z = acc[i][2] + bv.z; o.w = acc[i][3] + bv.w;
            *(float4*)&C[(size_t)m * Nout + n0] = o;
        }
    }
}

__global__ __launch_bounds__(256) void k_dwln_fb(
    const float* __restrict__ x, const float* __restrict__ dw_w,
    const float* __restrict__ dw_b, const float* __restrict__ ln_g,
    const float* __restrict__ ln_b, float* __restrict__ x1) {
    int l = blockIdx.x;
    int t = threadIdx.x;
    int w = l & 63, h = (l >> 6) & 63, n = l >> 12;
    float acc = dw_b[t];
#pragma unroll
    for (int kh = 0; kh < 3; ++kh) {
        int hh = h + kh - 1;
        if (hh < 0 || hh >= 64) continue;
#pragma unroll
        for (int kw = 0; kw < 3; ++kw) {
            int ww = w + kw - 1;
            if (ww < 0 || ww >= 64) continue;
            acc += x[(((n * 64 + hh) * 64) + ww) * CC + t] * dw_w[t * 9 + kh * 3 + kw];
        }
    }
    __shared__ float red[256];
    red[t] = acc;
    __syncthreads();
    for (int s = 128; s > 0; s >>= 1) {
        if (t < s) red[t] += red[t + s];
        __syncthreads();
    }
    float mean = red[0] * (1.0f / 256.0f);
    __syncthreads();
    float d = acc - mean;
    red[t] = d * d;
    __syncthreads();
    for (int s = 128; s > 0; s >>= 1) {
        if (t < s) red[t] += red[t + s];
        __syncthreads();
    }
    float var = red[0] * (1.0f / 256.0f);
    float xn = d * rsqrtf(var + 1e-6f) * ln_g[t] + ln_b[t];
    x1[l * CC + t] = 0.5f * xn * (1.0f + erff(xn * 0.70710678118654752f));
}

__device__ __forceinline__ float fetch_px_fb(const float* base, int yy, int xx) {
    if (xx < 0 || xx >= 64 || yy < 0 || yy >= 64) return 0.f;
    return base[(yy * 64 + xx) * CC];
}

__global__ __launch_bounds__(256) void k_gather_fb(
    const float* __restrict__ xp, const float* __restrict__ off,
    const float* __restrict__ logits, float* __restrict__ rows) {
    int l = blockIdx.x;
    int t = threadIdx.x;
    int w = l & 63, h = (l >> 6) & 63, n = l >> 12;
    __shared__ float offs[288];
    __shared__ float ms[144];
    offs[t] = off[(size_t)l * 288 + t];
    if (t < 32) offs[256 + t] = off[(size_t)l * 288 + 256 + t];
    if (t < 144) ms[t] = logits[(size_t)l * 144 + t];
    __syncthreads();
    if (t < 16) {
        int g = t;
        float mx = -1e30f;
#pragma unroll
        for (int p = 0; p < 9; ++p) mx = fmaxf(mx, ms[g * 9 + p]);
        float s = 0.f, e[9];
#pragma unroll
        for (int p = 0; p < 9; ++p) { e[p] = expf(ms[g * 9 + p] - mx); s += e[p]; }
        float inv = 1.0f / s;
#pragma unroll
        for (int p = 0; p < 9; ++p) ms[g * 9 + p] = e[p] * inv;
    }
    __syncthreads();
    int g = t >> 4;
    const float* base = xp + (size_t)n * 64 * 64 * CC + t;
    float acc = 0.f;
#pragma unroll
    for (int p = 0; p < 9; ++p) {
        float ox = offs[g * 18 + p * 2 + 0];
        float oy = offs[g * 18 + p * 2 + 1];
        float ax = (float)(w + (p / 3) - 1) + ox;
        float ay = (float)(h + (p % 3) - 1) + oy;
        float x0f = floorf(ax), y0f = floorf(ay);
        int x0 = (int)x0f, y0 = (int)y0f;
        float tx = ax - x0f, ty = ay - y0f;
        float v00 = fetch_px_fb(base, y0, x0);
        float v01 = fetch_px_fb(base, y0, x0 + 1);
        float v10 = fetch_px_fb(base, y0 + 1, x0);
        float v11 = fetch_px_fb(base, y0 + 1, x0 + 1);
        float bl = (v00 * (1.f - tx) + v01 * tx) * (1.f - ty) +
                   (v10 * (1.f - tx) + v11 * tx) * ty;
        acc += ms[g * 9 + p] * bl;
    }
    rows[(size_t)l * CC + t] = acc;
}

// ==========================================================================
extern "C" void kernel_launch(void* const* d_in, const int* in_sizes, int n_in,
                              void* d_out, int out_size, void* d_ws,
                              size_t ws_size, hipStream_t stream) {
    const float* x      = (const float*)d_in[0];
    const float* dw_w   = (const float*)d_in[1];
    const float* dw_b   = (const float*)d_in[2];
    const float* ln_g   = (const float*)d_in[3];
    const float* ln_b   = (const float*)d_in[4];
    const float* off_w  = (const float*)d_in[5];
    const float* off_b  = (const float*)d_in[6];
    const float* mask_w = (const float*)d_in[7];
    const float* mask_b = (const float*)d_in[8];
    const float* in_w   = (const float*)d_in[9];
    const float* in_b   = (const float*)d_in[10];
    const float* out_w  = (const float*)d_in[11];
    const float* out_b  = (const float*)d_in[12];
    float* out = (float*)d_out;

    const size_t szBF  = (size_t)LL * CC * 2;   // 16,777,216
    const size_t szF   = (size_t)LL * CC * 4;   // 33,554,432
    const size_t szOFF = (size_t)LL * 288 * 4;  // 37,748,736
    const size_t szLOG = (size_t)LL * 144 * 4;  // 18,874,368
    const size_t szWB  = 1100800;               // weight blob (padded)
    const size_t need  = 4 * szBF + szF + szOFF + szLOG + szWB;  // ~158.4 MB

    dim3 blk(256);
    if (ws_size >= need) {
        char* p = (char*)d_ws;
        bf16* xh  = (bf16*)p; p += szBF;
        bf16* xl  = (bf16*)p; p += szBF;
        bf16* x1h = (bf16*)p; p += szBF;
        bf16* x1l = (bf16*)p; p += szBF;
        float* xp   = (float*)p; p += szF;
        float* offv = (float*)p; p += szOFF;
        float* logi = (float*)p; p += szLOG;
        bf16* in_h  = (bf16*)p; p += 131072;
        bf16* in_l  = (bf16*)p; p += 131072;
        bf16* offw_h = (bf16*)p; p += 147456;
        bf16* offw_l = (bf16*)p; p += 147456;
        bf16* msk_h = (bf16*)p; p += 73728;
        bf16* msk_l = (bf16*)p; p += 73728;
        bf16* out_h = (bf16*)p; p += 131072;
        bf16* out_l = (bf16*)p; p += 131072;
        float* dwT  = (float*)p;
        bf16* rows_h = xh;   // xh/xl dead after in-proj GEMM
        bf16* rows_l = xl;

        k_dwt<<<dim3(9), blk, 0, stream>>>(dw_w, dwT);
        k_cvt<<<dim3(8192), blk, 0, stream>>>(x, xh, xl, 2097152);
        k_cvt<<<dim3(64), blk, 0, stream>>>(in_w, in_h, in_l, 16384);
        k_cvt<<<dim3(72), blk, 0, stream>>>(off_w, offw_h, offw_l, 18432);
        k_cvt<<<dim3(36), blk, 0, stream>>>(mask_w, msk_h, msk_l, 9216);
        k_cvt<<<dim3(64), blk, 0, stream>>>(out_w, out_h, out_l, 16384);
        k_dwln<<<dim3(LL / 4), blk, 0, stream>>>(x, dwT, dw_b, ln_g, ln_b, x1h, x1l);
        k_mfma_gemm<<<dim3(512, 1), blk, 0, stream>>>(xh, xl, in_h, in_l, in_b, xp, 256);
        k_mfma_gemm<<<dim3(512, 2), blk, 0, stream>>>(x1h, x1l, offw_h, offw_l, off_b, offv, 288);
        k_mfma_gemm<<<dim3(512, 1), blk, 0, stream>>>(x1h, x1l, msk_h, msk_l, mask_b, logi, 144);
        k_gather<<<dim3(LL / 4), blk, 0, stream>>>(xp, offv, logi, rows_h, rows_l);
        k_mfma_gemm<<<dim3(512, 1), blk, 0, stream>>>(rows_h, rows_l, out_h, out_l, out_b, out, 256);
    } else {
        // round-4 fp32 path (needs 123.7 MB, known to fit)
        char* p = (char*)d_ws;
        float* x1     = (float*)p; p += szF;
        float* xp     = (float*)p; p += szF;
        float* offv   = (float*)p; p += szOFF;
        float* logits = (float*)p;
        float* rows   = x1;
        k_dwln_fb<<<dim3(LL), blk, 0, stream>>>(x, dw_w, dw_b, ln_g, ln_b, x1);
        k_gemm256_fb<<<dim3(LL / 64, 4), blk, 0, stream>>>(x, in_w, in_b, xp, 256);
        k_gemm256_fb<<<dim3(LL / 64, 5), blk, 0, stream>>>(x1, off_w, off_b, offv, 288);
        k_gemm256_fb<<<dim3(LL / 64, 3), blk, 0, stream>>>(x1, mask_w, mask_b, logits, 144);
        k_gather_fb<<<dim3(LL), blk, 0, stream>>>(xp, offv, logits, rows);
        k_gemm256_fb<<<dim3(LL / 64, 4), blk, 0, stream>>>(rows, out_w, out_b, out, 256);
    }
}

// Round 6
// 271.334 us; speedup vs baseline: 13.1360x; 1.1933x over previous
//
#include <hip/hip_runtime.h>

// DCNv3 forward, FP32 I/O. N=8, H=W=64, C=256, G=16, GC=16, K=3, P=9. L=32768.
//
// Round-6:
//   k_prep  : all weight cvt/packing (in_w, [off_w;mask_w]->432-row head blob,
//             out_w, dwT transpose, packed head bias) in ONE launch
//   k_dwln  : dwconv3x3 + LN + GELU (wave/pixel) -> x1 hi/lo bf16
//   k_gemm<AF32> : 128x128-tile split-bf16 MFMA GEMM (3 products), BK=32;
//             AF32 variant converts fp32 A in staging (kills the big cvt pass)
//   k_gather: softmax + bilinear gather, 8 ch/thread -> rows hi/lo
// GEMMs: xp = x@in_w^T (N=256) ; head = x1@[off;mask]^T (N=432) ;
//        out = rows@out_w^T (N=256)
// Fallback: round-4 fp32 path if ws too small.

#define LL 32768
#define CC 256

typedef __bf16 bf16;
typedef __bf16 bf16x4 __attribute__((ext_vector_type(4)));
typedef __bf16 bf16x8 __attribute__((ext_vector_type(8)));
typedef float f32x4v __attribute__((ext_vector_type(4)));

// ---------------- weight prep: cvt + pack, one launch ---------------------
__global__ __launch_bounds__(256) void k_prep(
    const float* __restrict__ in_w, const float* __restrict__ off_w,
    const float* __restrict__ mask_w, const float* __restrict__ out_w,
    const float* __restrict__ dw_w, const float* __restrict__ off_b,
    const float* __restrict__ mask_b,
    bf16* __restrict__ in_h, bf16* __restrict__ in_l,
    bf16* __restrict__ hw_h, bf16* __restrict__ hw_l,
    bf16* __restrict__ out_h, bf16* __restrict__ out_l,
    float* __restrict__ dwT, float* __restrict__ hbias) {
    int idx = blockIdx.x * 256 + threadIdx.x;
    if (idx < 60416) {
        const float* s; bf16 *hi, *lo; int i;
        if (idx < 16384)      { s = in_w;   hi = in_h;          lo = in_l;          i = idx; }
        else if (idx < 34816) { s = off_w;  hi = hw_h;          lo = hw_l;          i = idx - 16384; }
        else if (idx < 44032) { s = mask_w; hi = hw_h + 73728;  lo = hw_l + 73728;  i = idx - 34816; }
        else                  { s = out_w;  hi = out_h;         lo = out_l;         i = idx - 44032; }
        float4 v = *(const float4*)(s + (size_t)i * 4);
        bf16x4 h, l;
        h[0] = (bf16)v.x; l[0] = (bf16)(v.x - (float)h[0]);
        h[1] = (bf16)v.y; l[1] = (bf16)(v.y - (float)h[1]);
        h[2] = (bf16)v.z; l[2] = (bf16)(v.z - (float)h[2]);
        h[3] = (bf16)v.w; l[3] = (bf16)(v.w - (float)h[3]);
        *(bf16x4*)(hi + (size_t)i * 4) = h;
        *(bf16x4*)(lo + (size_t)i * 4) = l;
    } else if (idx < 62720) {
        int e = idx - 60416;
        int c = e & 255, j = e >> 8;
        dwT[j * 256 + c] = dw_w[c * 9 + j];
    } else if (idx < 63152) {
        int e = idx - 62720;
        hbias[e] = (e < 288) ? off_b[e] : mask_b[e - 288];
    }
}

// ---------------- dwconv3x3 + LN + GELU: wave per pixel, 4 ch/thread ------
__global__ __launch_bounds__(256) void k_dwln(
    const float* __restrict__ x, const float* __restrict__ dwT,
    const float* __restrict__ dw_b, const float* __restrict__ ln_g,
    const float* __restrict__ ln_b, bf16* __restrict__ x1h,
    bf16* __restrict__ x1l) {
    int t = threadIdx.x;
    int q = t >> 6, u = t & 63;
    int l = blockIdx.x * 4 + q;
    int w = l & 63, h = (l >> 6) & 63, n = l >> 12;
    int c0 = u * 4;

    float4 acc = *(const float4*)(dw_b + c0);
#pragma unroll
    for (int kh = 0; kh < 3; ++kh) {
        int hh = h + kh - 1;
        if (hh < 0 || hh >= 64) continue;
#pragma unroll
        for (int kw = 0; kw < 3; ++kw) {
            int ww = w + kw - 1;
            if (ww < 0 || ww >= 64) continue;
            float4 xv = *(const float4*)(x + (size_t)(((n * 64 + hh) * 64) + ww) * CC + c0);
            float4 wv = *(const float4*)(dwT + (kh * 3 + kw) * 256 + c0);
            acc.x += xv.x * wv.x; acc.y += xv.y * wv.y;
            acc.z += xv.z * wv.z; acc.w += xv.w * wv.w;
        }
    }
    float s = acc.x + acc.y + acc.z + acc.w;
    float ss = acc.x * acc.x + acc.y * acc.y + acc.z * acc.z + acc.w * acc.w;
#pragma unroll
    for (int d = 1; d < 64; d <<= 1) {
        s += __shfl_xor(s, d);
        ss += __shfl_xor(ss, d);
    }
    float mean = s * (1.0f / 256.0f);
    float var = ss * (1.0f / 256.0f) - mean * mean;
    float rstd = rsqrtf(var + 1e-6f);
    float4 gv = *(const float4*)(ln_g + c0);
    float4 bv = *(const float4*)(ln_b + c0);
    float xn0 = (acc.x - mean) * rstd * gv.x + bv.x;
    float xn1 = (acc.y - mean) * rstd * gv.y + bv.y;
    float xn2 = (acc.z - mean) * rstd * gv.z + bv.z;
    float xn3 = (acc.w - mean) * rstd * gv.w + bv.w;
    float g0 = 0.5f * xn0 * (1.0f + erff(xn0 * 0.70710678118654752f));
    float g1 = 0.5f * xn1 * (1.0f + erff(xn1 * 0.70710678118654752f));
    float g2 = 0.5f * xn2 * (1.0f + erff(xn2 * 0.70710678118654752f));
    float g3 = 0.5f * xn3 * (1.0f + erff(xn3 * 0.70710678118654752f));
    bf16x4 oh, ol;
    oh[0] = (bf16)g0; ol[0] = (bf16)(g0 - (float)oh[0]);
    oh[1] = (bf16)g1; ol[1] = (bf16)(g1 - (float)oh[1]);
    oh[2] = (bf16)g2; ol[2] = (bf16)(g2 - (float)oh[2]);
    oh[3] = (bf16)g3; ol[3] = (bf16)(g3 - (float)oh[3]);
    *(bf16x4*)(x1h + (size_t)l * CC + c0) = oh;
    *(bf16x4*)(x1l + (size_t)l * CC + c0) = ol;
}

// ------------- 128x128-tile split-bf16 MFMA GEMM (3 products) -------------
// C[m][n] = A[m][:256].W[n][:256] + bias[n]; M=32768; grid=(M/128, ceil(N/128)).
// 4 waves in 2x2; each wave: 64x64 via 4x4 frags of 16x16x32.
template <bool AF32>
__global__ __launch_bounds__(256) void k_gemm(
    const float* __restrict__ A32, const bf16* __restrict__ Ah,
    const bf16* __restrict__ Al, const bf16* __restrict__ Wh,
    const bf16* __restrict__ Wl, const float* __restrict__ bias,
    float* __restrict__ C, int Nout) {
    int mb = blockIdx.x * 128, nb = blockIdx.y * 128;
    int t = threadIdx.x, wave = t >> 6, lane = t & 63;
    int wm = wave & 1, wn = wave >> 1;
    int fm = lane & 15, fq = lane >> 4;

    __shared__ bf16 sAh[128][32];
    __shared__ bf16 sAl[128][32];
    __shared__ bf16 sWh[128][32];
    __shared__ bf16 sWl[128][32];

    f32x4v acc[4][4];
#pragma unroll
    for (int i = 0; i < 4; ++i)
#pragma unroll
        for (int j = 0; j < 4; ++j) acc[i][j] = (f32x4v){0.f, 0.f, 0.f, 0.f};

    int r = t >> 1;            // staging row 0..127
    int cb = (t & 1) * 16;     // 16-elem half of the 32-k chunk

    for (int kc = 0; kc < 256; kc += 32) {
        if (AF32) {
            const float* src = A32 + (size_t)(mb + r) * CC + kc + cb;
#pragma unroll
            for (int j = 0; j < 4; ++j) {
                float4 v = *(const float4*)(src + j * 4);
                bf16x4 hh, ll;
                hh[0] = (bf16)v.x; ll[0] = (bf16)(v.x - (float)hh[0]);
                hh[1] = (bf16)v.y; ll[1] = (bf16)(v.y - (float)hh[1]);
                hh[2] = (bf16)v.z; ll[2] = (bf16)(v.z - (float)hh[2]);
                hh[3] = (bf16)v.w; ll[3] = (bf16)(v.w - (float)hh[3]);
                *(bf16x4*)&sAh[r][cb + j * 4] = hh;
                *(bf16x4*)&sAl[r][cb + j * 4] = ll;
            }
        } else {
            const bf16* srcH = Ah + (size_t)(mb + r) * CC + kc + cb;
            const bf16* srcL = Al + (size_t)(mb + r) * CC + kc + cb;
            *(uint4*)&sAh[r][cb]     = *(const uint4*)srcH;
            *(uint4*)&sAh[r][cb + 8] = *(const uint4*)(srcH + 8);
            *(uint4*)&sAl[r][cb]     = *(const uint4*)srcL;
            *(uint4*)&sAl[r][cb + 8] = *(const uint4*)(srcL + 8);
        }
        int wng = nb + r;
        if (wng < Nout) {
            const bf16* swH = Wh + (size_t)wng * CC + kc + cb;
            const bf16* swL = Wl + (size_t)wng * CC + kc + cb;
            *(uint4*)&sWh[r][cb]     = *(const uint4*)swH;
            *(uint4*)&sWh[r][cb + 8] = *(const uint4*)(swH + 8);
            *(uint4*)&sWl[r][cb]     = *(const uint4*)swL;
            *(uint4*)&sWl[r][cb + 8] = *(const uint4*)(swL + 8);
        } else {
            uint4 z = {0, 0, 0, 0};
            *(uint4*)&sWh[r][cb] = z; *(uint4*)&sWh[r][cb + 8] = z;
            *(uint4*)&sWl[r][cb] = z; *(uint4*)&sWl[r][cb + 8] = z;
        }
        __syncthreads();

        bf16x8 afh[4], afl[4], bfh[4], bfl[4];
#pragma unroll
        for (int i = 0; i < 4; ++i) {
            int ar = wm * 64 + i * 16 + fm;
            afh[i] = *(const bf16x8*)&sAh[ar][fq * 8];
            afl[i] = *(const bf16x8*)&sAl[ar][fq * 8];
        }
#pragma unroll
        for (int j = 0; j < 4; ++j) {
            int br = wn * 64 + j * 16 + fm;
            bfh[j] = *(const bf16x8*)&sWh[br][fq * 8];
            bfl[j] = *(const bf16x8*)&sWl[br][fq * 8];
        }
#pragma unroll
        for (int i = 0; i < 4; ++i)
#pragma unroll
            for (int j = 0; j < 4; ++j) {
                acc[i][j] = __builtin_amdgcn_mfma_f32_16x16x32_bf16(
                    afh[i], bfh[j], acc[i][j], 0, 0, 0);
                acc[i][j] = __builtin_amdgcn_mfma_f32_16x16x32_bf16(
                    afh[i], bfl[j], acc[i][j], 0, 0, 0);
                acc[i][j] = __builtin_amdgcn_mfma_f32_16x16x32_bf16(
                    afl[i], bfh[j], acc[i][j], 0, 0, 0);
            }
        __syncthreads();
    }

    // D mapping: m = 16*tile + fq*4 + reg, n = 16*tile + fm
#pragma unroll
    for (int j = 0; j < 4; ++j) {
        int n_g = nb + wn * 64 + j * 16 + fm;
        if (n_g >= Nout) continue;
        float bv = bias[n_g];
#pragma unroll
        for (int i = 0; i < 4; ++i) {
            int m_g = mb + wm * 64 + i * 16 + fq * 4;
#pragma unroll
            for (int rg = 0; rg < 4; ++rg)
                C[(size_t)(m_g + rg) * Nout + n_g] = acc[i][j][rg] + bv;
        }
    }
}

// ---------------- softmax + bilinear gather (8 ch/thread) -----------------
__global__ __launch_bounds__(256) void k_gather(
    const float* __restrict__ xp, const float* __restrict__ head,
    bf16* __restrict__ rh, bf16* __restrict__ rl) {
    int t = threadIdx.x;
    int q = t >> 5, u = t & 31;          // pixel-in-block, lane-in-pixel
    int l = blockIdx.x * 8 + q;
    int w = l & 63, h = (l >> 6) & 63, n = l >> 12;

    __shared__ float offs[8][288];
    __shared__ float ms[8][144];
    for (int j = u; j < 288; j += 32) offs[q][j] = head[(size_t)l * 432 + j];
    for (int j = u; j < 144; j += 32) ms[q][j] = head[(size_t)l * 432 + 288 + j];
    __syncthreads();

    if (u < 16) {
        int g = u;
        float mx = -1e30f;
#pragma unroll
        for (int p = 0; p < 9; ++p) mx = fmaxf(mx, ms[q][g * 9 + p]);
        float s = 0.f, e[9];
#pragma unroll
        for (int p = 0; p < 9; ++p) { e[p] = expf(ms[q][g * 9 + p] - mx); s += e[p]; }
        float inv = 1.0f / s;
#pragma unroll
        for (int p = 0; p < 9; ++p) ms[q][g * 9 + p] = e[p] * inv;
    }
    __syncthreads();

    int g = u >> 1;
    int c0 = g * 16 + (u & 1) * 8;
    const float* base = xp + (size_t)n * 4096 * CC + c0;
    float a0 = 0.f, a1 = 0.f, a2 = 0.f, a3 = 0.f;
    float a4 = 0.f, a5 = 0.f, a6 = 0.f, a7 = 0.f;
#pragma unroll
    for (int p = 0; p < 9; ++p) {
        float ox = offs[q][g * 18 + p * 2 + 0];
        float oy = offs[q][g * 18 + p * 2 + 1];
        float ax = (float)(w + (p / 3) - 1) + ox;
        float ay = (float)(h + (p % 3) - 1) + oy;
        float x0f = floorf(ax), y0f = floorf(ay);
        int x0 = (int)x0f, y0 = (int)y0f;
        float tx = ax - x0f, ty = ay - y0f;
        float m = ms[q][g * 9 + p];
        float cw[4];
        cw[0] = m * (1.f - tx) * (1.f - ty);
        cw[1] = m * tx * (1.f - ty);
        cw[2] = m * (1.f - tx) * ty;
        cw[3] = m * tx * ty;
#pragma unroll
        for (int cr = 0; cr < 4; ++cr) {
            int xx = x0 + (cr & 1), yy = y0 + (cr >> 1);
            if (xx >= 0 && xx < 64 && yy >= 0 && yy < 64) {
                const float* pp = base + (size_t)(yy * 64 + xx) * CC;
                float4 v0 = *(const float4*)pp;
                float4 v1 = *(const float4*)(pp + 4);
                float wt = cw[cr];
                a0 += wt * v0.x; a1 += wt * v0.y; a2 += wt * v0.z; a3 += wt * v0.w;
                a4 += wt * v1.x; a5 += wt * v1.y; a6 += wt * v1.z; a7 += wt * v1.w;
            }
        }
    }
    bf16x8 oh, ol;
    oh[0] = (bf16)a0; ol[0] = (bf16)(a0 - (float)oh[0]);
    oh[1] = (bf16)a1; ol[1] = (bf16)(a1 - (float)oh[1]);
    oh[2] = (bf16)a2; ol[2] = (bf16)(a2 - (float)oh[2]);
    oh[3] = (bf16)a3; ol[3] = (bf16)(a3 - (float)oh[3]);
    oh[4] = (bf16)a4; ol[4] = (bf16)(a4 - (float)oh[4]);
    oh[5] = (bf16)a5; ol[5] = (bf16)(a5 - (float)oh[5]);
    oh[6] = (bf16)a6; ol[6] = (bf16)(a6 - (float)oh[6]);
    oh[7] = (bf16)a7; ol[7] = (bf16)(a7 - (float)oh[7]);
    *(bf16x8*)(rh + (size_t)l * CC + c0) = oh;
    *(bf16x8*)(rl + (size_t)l * CC + c0) = ol;
}

// ======================= round-4 fallback (fp32) ==========================
__global__ __launch_bounds__(256) void k_gemm256_fb(
    const float* __restrict__ A, const float* __restrict__ W,
    const float* __restrict__ bias, float* __restrict__ C, int Nout) {
    int mb = blockIdx.x * 64;
    int nb = blockIdx.y * 64;
    int t = threadIdx.x;
    int tx = t & 15, ty = t >> 4;
    __shared__ float As[16][68];
    __shared__ float Ws[16][68];
    float acc[4][4];
#pragma unroll
    for (int i = 0; i < 4; ++i)
#pragma unroll
        for (int j = 0; j < 4; ++j) acc[i][j] = 0.f;
    int sm = t >> 2;
    int kq = (t & 3) * 4;
    const float* Arow = A + (size_t)(mb + sm) * CC + kq;
    const float* Wrow = W + (size_t)(nb + sm) * CC + kq;
    bool wvalid = (nb + sm) < Nout;
    for (int kc = 0; kc < 256; kc += 16) {
        float4 av = *(const float4*)(Arow + kc);
        float4 wv = wvalid ? *(const float4*)(Wrow + kc)
                           : make_float4(0.f, 0.f, 0.f, 0.f);
        As[kq + 0][sm] = av.x; As[kq + 1][sm] = av.y;
        As[kq + 2][sm] = av.z; As[kq + 3][sm] = av.w;
        Ws[kq + 0][sm] = wv.x; Ws[kq + 1][sm] = wv.y;
        Ws[kq + 2][sm] = wv.z; Ws[kq + 3][sm] = wv.w;
        __syncthreads();
#pragma unroll
        for (int kk = 0; kk < 16; ++kk) {
            float4 a = *(const float4*)&As[kk][ty * 4];
            float4 b = *(const float4*)&Ws[kk][tx * 4];
            acc[0][0] += a.x * b.x; acc[0][1] += a.x * b.y;
            acc[0][2] += a.x * b.z; acc[0][3] += a.x * b.w;
            acc[1][0] += a.y * b.x; acc[1][1] += a.y * b.y;
            acc[1][2] += a.y * b.z; acc[1][3] += a.y * b.w;
            acc[2][0] += a.z * b.x; acc[2][1] += a.z * b.y;
            acc[2][2] += a.z * b.z; acc[2][3] += a.z * b.w;
            acc[3][0] += a.w * b.x; acc[3][1] += a.w * b.y;
            acc[3][2] += a.w * b.z; acc[3][3] += a.w * b.w;
        }
        __syncthreads();
    }
    int n0 = nb + tx * 4;
    if (n0 + 4 <= Nout) {
        float4 bv = *(const float4*)&bias[n0];
#pragma unroll
        for (int i = 0; i < 4; ++i) {
            int m = mb + ty * 4 + i;
            float4 o;
            o.x = acc[i][0] + bv.x; o.y = acc[i][1] + bv.y;
            o.z = acc[i][2] + bv.z; o.w = acc[i][3] + bv.w;
            *(float4*)&C[(size_t)m * Nout + n0] = o;
        }
    }
}

__global__ __launch_bounds__(256) void k_dwln_fb(
    const float* __restrict__ x, const float* __restrict__ dw_w,
    const float* __restrict__ dw_b, const float* __restrict__ ln_g,
    const float* __restrict__ ln_b, float* __restrict__ x1) {
    int l = blockIdx.x;
    int t = threadIdx.x;
    int w = l & 63, h = (l >> 6) & 63, n = l >> 12;
    float acc = dw_b[t];
#pragma unroll
    for (int kh = 0; kh < 3; ++kh) {
        int hh = h + kh - 1;
        if (hh < 0 || hh >= 64) continue;
#pragma unroll
        for (int kw = 0; kw < 3; ++kw) {
            int ww = w + kw - 1;
            if (ww < 0 || ww >= 64) continue;
            acc += x[(((n * 64 + hh) * 64) + ww) * CC + t] * dw_w[t * 9 + kh * 3 + kw];
        }
    }
    __shared__ float red[256];
    red[t] = acc;
    __syncthreads();
    for (int s = 128; s > 0; s >>= 1) {
        if (t < s) red[t] += red[t + s];
        __syncthreads();
    }
    float mean = red[0] * (1.0f / 256.0f);
    __syncthreads();
    float d = acc - mean;
    red[t] = d * d;
    __syncthreads();
    for (int s = 128; s > 0; s >>= 1) {
        if (t < s) red[t] += red[t + s];
        __syncthreads();
    }
    float var = red[0] * (1.0f / 256.0f);
    float xn = d * rsqrtf(var + 1e-6f) * ln_g[t] + ln_b[t];
    x1[l * CC + t] = 0.5f * xn * (1.0f + erff(xn * 0.70710678118654752f));
}

__device__ __forceinline__ float fetch_px_fb(const float* base, int yy, int xx) {
    if (xx < 0 || xx >= 64 || yy < 0 || yy >= 64) return 0.f;
    return base[(yy * 64 + xx) * CC];
}

__global__ __launch_bounds__(256) void k_gather_fb(
    const float* __restrict__ xp, const float* __restrict__ off,
    const float* __restrict__ logits, float* __restrict__ rows) {
    int l = blockIdx.x;
    int t = threadIdx.x;
    int w = l & 63, h = (l >> 6) & 63, n = l >> 12;
    __shared__ float offs[288];
    __shared__ float ms[144];
    offs[t] = off[(size_t)l * 288 + t];
    if (t < 32) offs[256 + t] = off[(size_t)l * 288 + 256 + t];
    if (t < 144) ms[t] = logits[(size_t)l * 144 + t];
    __syncthreads();
    if (t < 16) {
        int g = t;
        float mx = -1e30f;
#pragma unroll
        for (int p = 0; p < 9; ++p) mx = fmaxf(mx, ms[g * 9 + p]);
        float s = 0.f, e[9];
#pragma unroll
        for (int p = 0; p < 9; ++p) { e[p] = expf(ms[g * 9 + p] - mx); s += e[p]; }
        float inv = 1.0f / s;
#pragma unroll
        for (int p = 0; p < 9; ++p) ms[g * 9 + p] = e[p] * inv;
    }
    __syncthreads();
    int g = t >> 4;
    const float* base = xp + (size_t)n * 64 * 64 * CC + t;
    float acc = 0.f;
#pragma unroll
    for (int p = 0; p < 9; ++p) {
        float ox = offs[g * 18 + p * 2 + 0];
        float oy = offs[g * 18 + p * 2 + 1];
        float ax = (float)(w + (p / 3) - 1) + ox;
        float ay = (float)(h + (p % 3) - 1) + oy;
        float x0f = floorf(ax), y0f = floorf(ay);
        int x0 = (int)x0f, y0 = (int)y0f;
        float tx = ax - x0f, ty = ay - y0f;
        float v00 = fetch_px_fb(base, y0, x0);
        float v01 = fetch_px_fb(base, y0, x0 + 1);
        float v10 = fetch_px_fb(base, y0 + 1, x0);
        float v11 = fetch_px_fb(base, y0 + 1, x0 + 1);
        float bl = (v00 * (1.f - tx) + v01 * tx) * (1.f - ty) +
                   (v10 * (1.f - tx) + v11 * tx) * ty;
        acc += ms[g * 9 + p] * bl;
    }
    rows[(size_t)l * CC + t] = acc;
}

// ==========================================================================
extern "C" void kernel_launch(void* const* d_in, const int* in_sizes, int n_in,
                              void* d_out, int out_size, void* d_ws,
                              size_t ws_size, hipStream_t stream) {
    const float* x      = (const float*)d_in[0];
    const float* dw_w   = (const float*)d_in[1];
    const float* dw_b   = (const float*)d_in[2];
    const float* ln_g   = (const float*)d_in[3];
    const float* ln_b   = (const float*)d_in[4];
    const float* off_w  = (const float*)d_in[5];
    const float* off_b  = (const float*)d_in[6];
    const float* mask_w = (const float*)d_in[7];
    const float* mask_b = (const float*)d_in[8];
    const float* in_w   = (const float*)d_in[9];
    const float* in_b   = (const float*)d_in[10];
    const float* out_w  = (const float*)d_in[11];
    const float* out_b  = (const float*)d_in[12];
    float* out = (float*)d_out;

    const size_t szBF   = (size_t)LL * CC * 2;   // 16,777,216
    const size_t szF    = (size_t)LL * CC * 4;   // 33,554,432
    const size_t szHEAD = (size_t)LL * 432 * 4;  // 56,623,104
    const size_t szOFF  = (size_t)LL * 288 * 4;
    const size_t szLOG  = (size_t)LL * 144 * 4;
    const size_t szWB   = 1048576;               // weight blob (padded)
    const size_t need   = 2 * szBF + szF + szHEAD + szWB;  // ~125 MB

    dim3 blk(256);
    if (ws_size >= need) {
        char* p = (char*)d_ws;
        bf16* x1h = (bf16*)p; p += szBF;
        bf16* x1l = (bf16*)p; p += szBF;
        float* xp   = (float*)p; p += szF;
        float* head = (float*)p; p += szHEAD;
        bf16* in_h  = (bf16*)p; p += 131072;
        bf16* in_l  = (bf16*)p; p += 131072;
        bf16* hw_h  = (bf16*)p; p += 221184;   // 432 x 256 bf16
        bf16* hw_l  = (bf16*)p; p += 221184;
        bf16* out_h = (bf16*)p; p += 131072;
        bf16* out_l = (bf16*)p; p += 131072;
        float* dwT  = (float*)p; p += 9216;
        float* hbias = (float*)p;
        bf16* rows_h = x1h;   // x1 dead after head GEMM
        bf16* rows_l = x1l;

        k_prep<<<dim3(247), blk, 0, stream>>>(in_w, off_w, mask_w, out_w, dw_w,
                                              off_b, mask_b, in_h, in_l, hw_h,
                                              hw_l, out_h, out_l, dwT, hbias);
        k_dwln<<<dim3(LL / 4), blk, 0, stream>>>(x, dwT, dw_b, ln_g, ln_b, x1h, x1l);
        k_gemm<true><<<dim3(256, 2), blk, 0, stream>>>(
            x, nullptr, nullptr, in_h, in_l, in_b, xp, 256);
        k_gemm<false><<<dim3(256, 4), blk, 0, stream>>>(
            nullptr, x1h, x1l, hw_h, hw_l, hbias, head, 432);
        k_gather<<<dim3(LL / 8), blk, 0, stream>>>(xp, head, rows_h, rows_l);
        k_gemm<false><<<dim3(256, 2), blk, 0, stream>>>(
            nullptr, rows_h, rows_l, out_h, out_l, out_b, out, 256);
    } else {
        // round-4 fp32 path (needs 123.7 MB)
        char* p = (char*)d_ws;
        float* x1     = (float*)p; p += szF;
        float* xp     = (float*)p; p += szF;
        float* offv   = (float*)p; p += szOFF;
        float* logits = (float*)p;
        float* rows   = x1;
        k_dwln_fb<<<dim3(LL), blk, 0, stream>>>(x, dw_w, dw_b, ln_g, ln_b, x1);
        k_gemm256_fb<<<dim3(LL / 64, 4), blk, 0, stream>>>(x, in_w, in_b, xp, 256);
        k_gemm256_fb<<<dim3(LL / 64, 5), blk, 0, stream>>>(x1, off_w, off_b, offv, 288);
        k_gemm256_fb<<<dim3(LL / 64, 3), blk, 0, stream>>>(x1, mask_w, mask_b, logits, 144);
        k_gather_fb<<<dim3(LL), blk, 0, stream>>>(xp, offv, logits, rows);
        k_gemm256_fb<<<dim3(LL / 64, 4), blk, 0, stream>>>(rows, out_w, out_b, out, 256);
    }
}

// Round 7
// 228.539 us; speedup vs baseline: 15.5958x; 1.1873x over previous
//
#include <hip/hip_runtime.h>

// DCNv3 forward, FP32 I/O. N=8, H=W=64, C=256, G=16, GC=16, K=3, P=9. L=32768.
//
// Round-7:
//  - 2-product split GEMM: A plain bf16, W = hi+lo bf16 (error ~6e-4/GEMM).
//    acc = mfma(a, wh) ; acc = mfma(a, wl).   MFMA work -33% vs round 6.
//  - xp stored as bf16 by the in-proj GEMM epilogue -> gather traffic halved.
//  - gather: branch-free clamped corner loads (validity folded into weight),
//    output plain bf16 rows (no lo half).
// Dispatches: k_prep, k_dwln, gemm(in), gemm(head N=432), k_gather, gemm(out).
// Fallback: round-3 minimal path (33.5 MB) if ws too small.

#define LL 32768
#define CC 256

typedef __bf16 bf16;
typedef __bf16 bf16x4 __attribute__((ext_vector_type(4)));
typedef __bf16 bf16x8 __attribute__((ext_vector_type(8)));
typedef float f32x4v __attribute__((ext_vector_type(4)));

// ---------------- weight prep: cvt + pack, one launch ---------------------
__global__ __launch_bounds__(256) void k_prep(
    const float* __restrict__ in_w, const float* __restrict__ off_w,
    const float* __restrict__ mask_w, const float* __restrict__ out_w,
    const float* __restrict__ dw_w, const float* __restrict__ off_b,
    const float* __restrict__ mask_b,
    bf16* __restrict__ in_h, bf16* __restrict__ in_l,
    bf16* __restrict__ hw_h, bf16* __restrict__ hw_l,
    bf16* __restrict__ out_h, bf16* __restrict__ out_l,
    float* __restrict__ dwT, float* __restrict__ hbias) {
    int idx = blockIdx.x * 256 + threadIdx.x;
    if (idx < 60416) {
        const float* s; bf16 *hi, *lo; int i;
        if (idx < 16384)      { s = in_w;   hi = in_h;          lo = in_l;          i = idx; }
        else if (idx < 34816) { s = off_w;  hi = hw_h;          lo = hw_l;          i = idx - 16384; }
        else if (idx < 44032) { s = mask_w; hi = hw_h + 73728;  lo = hw_l + 73728;  i = idx - 34816; }
        else                  { s = out_w;  hi = out_h;         lo = out_l;         i = idx - 44032; }
        float4 v = *(const float4*)(s + (size_t)i * 4);
        bf16x4 h, l;
        h[0] = (bf16)v.x; l[0] = (bf16)(v.x - (float)h[0]);
        h[1] = (bf16)v.y; l[1] = (bf16)(v.y - (float)h[1]);
        h[2] = (bf16)v.z; l[2] = (bf16)(v.z - (float)h[2]);
        h[3] = (bf16)v.w; l[3] = (bf16)(v.w - (float)h[3]);
        *(bf16x4*)(hi + (size_t)i * 4) = h;
        *(bf16x4*)(lo + (size_t)i * 4) = l;
    } else if (idx < 62720) {
        int e = idx - 60416;
        int c = e & 255, j = e >> 8;
        dwT[j * 256 + c] = dw_w[c * 9 + j];
    } else if (idx < 63152) {
        int e = idx - 62720;
        hbias[e] = (e < 288) ? off_b[e] : mask_b[e - 288];
    }
}

// ---------------- dwconv3x3 + LN + GELU: wave per pixel, 4 ch/thread ------
__global__ __launch_bounds__(256) void k_dwln(
    const float* __restrict__ x, const float* __restrict__ dwT,
    const float* __restrict__ dw_b, const float* __restrict__ ln_g,
    const float* __restrict__ ln_b, bf16* __restrict__ x1h) {
    int t = threadIdx.x;
    int q = t >> 6, u = t & 63;
    int l = blockIdx.x * 4 + q;
    int w = l & 63, h = (l >> 6) & 63, n = l >> 12;
    int c0 = u * 4;

    float4 acc = *(const float4*)(dw_b + c0);
#pragma unroll
    for (int kh = 0; kh < 3; ++kh) {
        int hh = h + kh - 1;
        if (hh < 0 || hh >= 64) continue;
#pragma unroll
        for (int kw = 0; kw < 3; ++kw) {
            int ww = w + kw - 1;
            if (ww < 0 || ww >= 64) continue;
            float4 xv = *(const float4*)(x + (size_t)(((n * 64 + hh) * 64) + ww) * CC + c0);
            float4 wv = *(const float4*)(dwT + (kh * 3 + kw) * 256 + c0);
            acc.x += xv.x * wv.x; acc.y += xv.y * wv.y;
            acc.z += xv.z * wv.z; acc.w += xv.w * wv.w;
        }
    }
    float s = acc.x + acc.y + acc.z + acc.w;
    float ss = acc.x * acc.x + acc.y * acc.y + acc.z * acc.z + acc.w * acc.w;
#pragma unroll
    for (int d = 1; d < 64; d <<= 1) {
        s += __shfl_xor(s, d);
        ss += __shfl_xor(ss, d);
    }
    float mean = s * (1.0f / 256.0f);
    float var = ss * (1.0f / 256.0f) - mean * mean;
    float rstd = rsqrtf(var + 1e-6f);
    float4 gv = *(const float4*)(ln_g + c0);
    float4 bv = *(const float4*)(ln_b + c0);
    float xn0 = (acc.x - mean) * rstd * gv.x + bv.x;
    float xn1 = (acc.y - mean) * rstd * gv.y + bv.y;
    float xn2 = (acc.z - mean) * rstd * gv.z + bv.z;
    float xn3 = (acc.w - mean) * rstd * gv.w + bv.w;
    bf16x4 oh;
    oh[0] = (bf16)(0.5f * xn0 * (1.0f + erff(xn0 * 0.70710678118654752f)));
    oh[1] = (bf16)(0.5f * xn1 * (1.0f + erff(xn1 * 0.70710678118654752f)));
    oh[2] = (bf16)(0.5f * xn2 * (1.0f + erff(xn2 * 0.70710678118654752f)));
    oh[3] = (bf16)(0.5f * xn3 * (1.0f + erff(xn3 * 0.70710678118654752f)));
    *(bf16x4*)(x1h + (size_t)l * CC + c0) = oh;
}

// ---- 128x128-tile 2-product split-bf16 MFMA GEMM: C = A@W^T + bias -------
// A: bf16 (or fp32 converted in staging). W: hi/lo bf16. K=256, BK=32.
template <bool AF32, bool OBF16>
__global__ __launch_bounds__(256) void k_gemm(
    const float* __restrict__ A32, const bf16* __restrict__ Abf,
    const bf16* __restrict__ Wh, const bf16* __restrict__ Wl,
    const float* __restrict__ bias, float* __restrict__ C32,
    bf16* __restrict__ Cbf, int Nout) {
    int mb = blockIdx.x * 128, nb = blockIdx.y * 128;
    int t = threadIdx.x, wave = t >> 6, lane = t & 63;
    int wm = wave & 1, wn = wave >> 1;
    int fm = lane & 15, fq = lane >> 4;

    __shared__ bf16 sA[128][32];
    __shared__ bf16 sWh[128][32];
    __shared__ bf16 sWl[128][32];

    f32x4v acc[4][4];
#pragma unroll
    for (int i = 0; i < 4; ++i)
#pragma unroll
        for (int j = 0; j < 4; ++j) acc[i][j] = (f32x4v){0.f, 0.f, 0.f, 0.f};

    int r = t >> 1;            // staging row 0..127
    int cb = (t & 1) * 16;     // 16-elem half of the 32-k chunk

    for (int kc = 0; kc < 256; kc += 32) {
        if (AF32) {
            const float* src = A32 + (size_t)(mb + r) * CC + kc + cb;
#pragma unroll
            for (int j = 0; j < 2; ++j) {
                float4 v0 = *(const float4*)(src + j * 8);
                float4 v1 = *(const float4*)(src + j * 8 + 4);
                bf16x8 hh;
                hh[0] = (bf16)v0.x; hh[1] = (bf16)v0.y;
                hh[2] = (bf16)v0.z; hh[3] = (bf16)v0.w;
                hh[4] = (bf16)v1.x; hh[5] = (bf16)v1.y;
                hh[6] = (bf16)v1.z; hh[7] = (bf16)v1.w;
                *(bf16x8*)&sA[r][cb + j * 8] = hh;
            }
        } else {
            const bf16* srcA = Abf + (size_t)(mb + r) * CC + kc + cb;
            *(uint4*)&sA[r][cb]     = *(const uint4*)srcA;
            *(uint4*)&sA[r][cb + 8] = *(const uint4*)(srcA + 8);
        }
        int wng = nb + r;
        if (wng < Nout) {
            const bf16* swH = Wh + (size_t)wng * CC + kc + cb;
            const bf16* swL = Wl + (size_t)wng * CC + kc + cb;
            *(uint4*)&sWh[r][cb]     = *(const uint4*)swH;
            *(uint4*)&sWh[r][cb + 8] = *(const uint4*)(swH + 8);
            *(uint4*)&sWl[r][cb]     = *(const uint4*)swL;
            *(uint4*)&sWl[r][cb + 8] = *(const uint4*)(swL + 8);
        } else {
            uint4 z = {0, 0, 0, 0};
            *(uint4*)&sWh[r][cb] = z; *(uint4*)&sWh[r][cb + 8] = z;
            *(uint4*)&sWl[r][cb] = z; *(uint4*)&sWl[r][cb + 8] = z;
        }
        __syncthreads();

        bf16x8 af[4], bfh[4], bfl[4];
#pragma unroll
        for (int i = 0; i < 4; ++i)
            af[i] = *(const bf16x8*)&sA[wm * 64 + i * 16 + fm][fq * 8];
#pragma unroll
        for (int j = 0; j < 4; ++j) {
            int br = wn * 64 + j * 16 + fm;
            bfh[j] = *(const bf16x8*)&sWh[br][fq * 8];
            bfl[j] = *(const bf16x8*)&sWl[br][fq * 8];
        }
#pragma unroll
        for (int i = 0; i < 4; ++i)
#pragma unroll
            for (int j = 0; j < 4; ++j) {
                acc[i][j] = __builtin_amdgcn_mfma_f32_16x16x32_bf16(
                    af[i], bfh[j], acc[i][j], 0, 0, 0);
                acc[i][j] = __builtin_amdgcn_mfma_f32_16x16x32_bf16(
                    af[i], bfl[j], acc[i][j], 0, 0, 0);
            }
        __syncthreads();
    }

    // D mapping: m = 16*tile + fq*4 + reg, n = 16*tile + fm
#pragma unroll
    for (int j = 0; j < 4; ++j) {
        int n_g = nb + wn * 64 + j * 16 + fm;
        if (n_g >= Nout) continue;
        float bv = bias[n_g];
#pragma unroll
        for (int i = 0; i < 4; ++i) {
            int m_g = mb + wm * 64 + i * 16 + fq * 4;
#pragma unroll
            for (int rg = 0; rg < 4; ++rg) {
                float o = acc[i][j][rg] + bv;
                if (OBF16)
                    Cbf[(size_t)(m_g + rg) * Nout + n_g] = (bf16)o;
                else
                    C32[(size_t)(m_g + rg) * Nout + n_g] = o;
            }
        }
    }
}

// ------ softmax + bilinear gather (8 ch/thread, bf16 xp, branch-free) -----
__global__ __launch_bounds__(256) void k_gather(
    const bf16* __restrict__ xp, const float* __restrict__ head,
    bf16* __restrict__ rows) {
    int t = threadIdx.x;
    int q = t >> 5, u = t & 31;          // pixel-in-block, lane-in-pixel
    int l = blockIdx.x * 8 + q;
    int w = l & 63, h = (l >> 6) & 63, n = l >> 12;

    __shared__ float offs[8][288];
    __shared__ float ms[8][144];
    for (int j = u; j < 288; j += 32) offs[q][j] = head[(size_t)l * 432 + j];
    for (int j = u; j < 144; j += 32) ms[q][j] = head[(size_t)l * 432 + 288 + j];
    __syncthreads();

    if (u < 16) {
        int g = u;
        float mx = -1e30f;
#pragma unroll
        for (int p = 0; p < 9; ++p) mx = fmaxf(mx, ms[q][g * 9 + p]);
        float s = 0.f, e[9];
#pragma unroll
        for (int p = 0; p < 9; ++p) { e[p] = expf(ms[q][g * 9 + p] - mx); s += e[p]; }
        float inv = 1.0f / s;
#pragma unroll
        for (int p = 0; p < 9; ++p) ms[q][g * 9 + p] = e[p] * inv;
    }
    __syncthreads();

    int g = u >> 1;
    int c0 = g * 16 + (u & 1) * 8;
    const bf16* base = xp + (size_t)n * 4096 * CC + c0;
    float a0 = 0.f, a1 = 0.f, a2 = 0.f, a3 = 0.f;
    float a4 = 0.f, a5 = 0.f, a6 = 0.f, a7 = 0.f;
#pragma unroll
    for (int p = 0; p < 9; ++p) {
        float ox = offs[q][g * 18 + p * 2 + 0];
        float oy = offs[q][g * 18 + p * 2 + 1];
        float ax = (float)(w + (p / 3) - 1) + ox;
        float ay = (float)(h + (p % 3) - 1) + oy;
        float x0f = floorf(ax), y0f = floorf(ay);
        int x0 = (int)x0f, y0 = (int)y0f;
        float tx = ax - x0f, ty = ay - y0f;
        float m = ms[q][g * 9 + p];
        // branch-free: clamp indices, zero weights for OOB corners
        int idx[4]; float cw[4];
#pragma unroll
        for (int cr = 0; cr < 4; ++cr) {
            int xx = x0 + (cr & 1), yy = y0 + (cr >> 1);
            bool v = (xx >= 0) & (xx < 64) & (yy >= 0) & (yy < 64);
            int xc = min(max(xx, 0), 63), yc = min(max(yy, 0), 63);
            idx[cr] = (yc * 64 + xc) * CC;
            float wx = (cr & 1) ? tx : (1.f - tx);
            float wy = (cr >> 1) ? ty : (1.f - ty);
            cw[cr] = v ? (m * wx * wy) : 0.f;
        }
#pragma unroll
        for (int cr = 0; cr < 4; ++cr) {
            bf16x8 vb = *(const bf16x8*)(base + idx[cr]);
            float wt = cw[cr];
            a0 += wt * (float)vb[0]; a1 += wt * (float)vb[1];
            a2 += wt * (float)vb[2]; a3 += wt * (float)vb[3];
            a4 += wt * (float)vb[4]; a5 += wt * (float)vb[5];
            a6 += wt * (float)vb[6]; a7 += wt * (float)vb[7];
        }
    }
    bf16x8 oh;
    oh[0] = (bf16)a0; oh[1] = (bf16)a1; oh[2] = (bf16)a2; oh[3] = (bf16)a3;
    oh[4] = (bf16)a4; oh[5] = (bf16)a5; oh[6] = (bf16)a6; oh[7] = (bf16)a7;
    *(bf16x8*)(rows + (size_t)l * CC + c0) = oh;
}

// ======================= round-3 minimal fallback =========================
__device__ __forceinline__ float dot256f(const float* a, const float* wrow) {
    const float4* w4 = (const float4*)wrow;
    float s = 0.f;
#pragma unroll 16
    for (int i = 0; i < 64; ++i) {
        float4 u = w4[i];
        const float* ap = a + i * 4;
        s += ap[0] * u.x + ap[1] * u.y + ap[2] * u.z + ap[3] * u.w;
    }
    return s;
}

__global__ __launch_bounds__(256) void k_inproj_fb(
    const float* __restrict__ x, const float* __restrict__ in_w,
    const float* __restrict__ in_b, float* __restrict__ xp) {
    int l = blockIdx.x;
    int t = threadIdx.x;
    __shared__ float xa[256];
    xa[t] = x[l * CC + t];
    __syncthreads();
    xp[l * CC + t] = dot256f(xa, in_w + t * CC) + in_b[t];
}

__device__ __forceinline__ float fetch_px_fb(const float* base, int yy, int xx) {
    if (xx < 0 || xx >= 64 || yy < 0 || yy >= 64) return 0.f;
    return base[(yy * 64 + xx) * CC];
}

__global__ __launch_bounds__(256) void k_main_fb(
    const float* __restrict__ x, const float* __restrict__ xp,
    const float* __restrict__ dw_w, const float* __restrict__ dw_b,
    const float* __restrict__ ln_g, const float* __restrict__ ln_b,
    const float* __restrict__ off_w, const float* __restrict__ off_b,
    const float* __restrict__ mask_w, const float* __restrict__ mask_b,
    const float* __restrict__ out_w, const float* __restrict__ out_b,
    float* __restrict__ out) {
    int l = blockIdx.x;
    int t = threadIdx.x;
    int w = l & 63, h = (l >> 6) & 63, n = l >> 12;
    __shared__ float x1[256];
    __shared__ float red[256];
    __shared__ float offs[288];
    __shared__ float ms[144];
    __shared__ float row[256];

    float acc = dw_b[t];
#pragma unroll
    for (int kh = 0; kh < 3; ++kh) {
        int hh = h + kh - 1;
        if (hh < 0 || hh >= 64) continue;
#pragma unroll
        for (int kw = 0; kw < 3; ++kw) {
            int ww = w + kw - 1;
            if (ww < 0 || ww >= 64) continue;
            acc += x[(((n * 64 + hh) * 64) + ww) * CC + t] * dw_w[t * 9 + kh * 3 + kw];
        }
    }
    red[t] = acc;
    __syncthreads();
    for (int s = 128; s > 0; s >>= 1) {
        if (t < s) red[t] += red[t + s];
        __syncthreads();
    }
    float mean = red[0] * (1.0f / 256.0f);
    __syncthreads();
    float d = acc - mean;
    red[t] = d * d;
    __syncthreads();
    for (int s = 128; s > 0; s >>= 1) {
        if (t < s) red[t] += red[t + s];
        __syncthreads();
    }
    float var = red[0] * (1.0f / 256.0f);
    float xn = d * rsqrtf(var + 1e-6f) * ln_g[t] + ln_b[t];
    x1[t] = 0.5f * xn * (1.0f + erff(xn * 0.70710678118654752f));
    __syncthreads();

    offs[t] = dot256f(x1, off_w + t * CC) + off_b[t];
    if (t < 32) {
        int j = 256 + t;
        offs[j] = dot256f(x1, off_w + j * CC) + off_b[j];
    }
    if (t < 144) ms[t] = dot256f(x1, mask_w + t * CC) + mask_b[t];
    __syncthreads();

    if (t < 16) {
        int g = t;
        float mx = -1e30f;
#pragma unroll
        for (int p = 0; p < 9; ++p) mx = fmaxf(mx, ms[g * 9 + p]);
        float s = 0.f, e[9];
#pragma unroll
        for (int p = 0; p < 9; ++p) { e[p] = expf(ms[g * 9 + p] - mx); s += e[p]; }
        float inv = 1.0f / s;
#pragma unroll
        for (int p = 0; p < 9; ++p) ms[g * 9 + p] = e[p] * inv;
    }
    __syncthreads();

    int g = t >> 4;
    const float* base = xp + (size_t)n * 64 * 64 * CC + t;
    float acc2 = 0.f;
#pragma unroll
    for (int p = 0; p < 9; ++p) {
        float ox = offs[g * 18 + p * 2 + 0];
        float oy = offs[g * 18 + p * 2 + 1];
        float ax = (float)(w + (p / 3) - 1) + ox;
        float ay = (float)(h + (p % 3) - 1) + oy;
        float x0f = floorf(ax), y0f = floorf(ay);
        int x0 = (int)x0f, y0 = (int)y0f;
        float tx = ax - x0f, ty = ay - y0f;
        float v00 = fetch_px_fb(base, y0, x0);
        float v01 = fetch_px_fb(base, y0, x0 + 1);
        float v10 = fetch_px_fb(base, y0 + 1, x0);
        float v11 = fetch_px_fb(base, y0 + 1, x0 + 1);
        float bl = (v00 * (1.f - tx) + v01 * tx) * (1.f - ty) +
                   (v10 * (1.f - tx) + v11 * tx) * ty;
        acc2 += ms[g * 9 + p] * bl;
    }
    row[t] = acc2;
    __syncthreads();
    out[l * CC + t] = dot256f(row, out_w + t * CC) + out_b[t];
}

// ==========================================================================
extern "C" void kernel_launch(void* const* d_in, const int* in_sizes, int n_in,
                              void* d_out, int out_size, void* d_ws,
                              size_t ws_size, hipStream_t stream) {
    const float* x      = (const float*)d_in[0];
    const float* dw_w   = (const float*)d_in[1];
    const float* dw_b   = (const float*)d_in[2];
    const float* ln_g   = (const float*)d_in[3];
    const float* ln_b   = (const float*)d_in[4];
    const float* off_w  = (const float*)d_in[5];
    const float* off_b  = (const float*)d_in[6];
    const float* mask_w = (const float*)d_in[7];
    const float* mask_b = (const float*)d_in[8];
    const float* in_w   = (const float*)d_in[9];
    const float* in_b   = (const float*)d_in[10];
    const float* out_w  = (const float*)d_in[11];
    const float* out_b  = (const float*)d_in[12];
    float* out = (float*)d_out;

    const size_t szBF   = (size_t)LL * CC * 2;   // 16,777,216
    const size_t szHEAD = (size_t)LL * 432 * 4;  // 56,623,104
    const size_t szWB   = 1048576;
    const size_t need   = 2 * szBF + szHEAD + szWB;  // ~91.2 MB

    dim3 blk(256);
    if (ws_size >= need) {
        char* p = (char*)d_ws;
        bf16* x1h = (bf16*)p; p += szBF;       // reused as rows after head GEMM
        bf16* xpb = (bf16*)p; p += szBF;
        float* head = (float*)p; p += szHEAD;
        bf16* in_h  = (bf16*)p; p += 131072;
        bf16* in_l  = (bf16*)p; p += 131072;
        bf16* hw_h  = (bf16*)p; p += 221184;   // 432 x 256 bf16
        bf16* hw_l  = (bf16*)p; p += 221184;
        bf16* out_h = (bf16*)p; p += 131072;
        bf16* out_l = (bf16*)p; p += 131072;
        float* dwT  = (float*)p; p += 9216;
        float* hbias = (float*)p;
        bf16* rows = x1h;

        k_prep<<<dim3(247), blk, 0, stream>>>(in_w, off_w, mask_w, out_w, dw_w,
                                              off_b, mask_b, in_h, in_l, hw_h,
                                              hw_l, out_h, out_l, dwT, hbias);
        k_dwln<<<dim3(LL / 4), blk, 0, stream>>>(x, dwT, dw_b, ln_g, ln_b, x1h);
        k_gemm<true, true><<<dim3(256, 2), blk, 0, stream>>>(
            x, nullptr, in_h, in_l, in_b, nullptr, xpb, 256);
        k_gemm<false, false><<<dim3(256, 4), blk, 0, stream>>>(
            nullptr, x1h, hw_h, hw_l, hbias, head, nullptr, 432);
        k_gather<<<dim3(LL / 8), blk, 0, stream>>>(xpb, head, rows);
        k_gemm<false, false><<<dim3(256, 2), blk, 0, stream>>>(
            nullptr, rows, out_h, out_l, out_b, out, nullptr, 256);
    } else {
        float* xp = (float*)d_ws;   // 33.5 MB
        k_inproj_fb<<<dim3(LL), blk, 0, stream>>>(x, in_w, in_b, xp);
        k_main_fb<<<dim3(LL), blk, 0, stream>>>(x, xp, dw_w, dw_b, ln_g, ln_b,
                                                off_w, off_b, mask_w, mask_b,
                                                out_w, out_b, out);
    }
}

// Round 8
// 218.766 us; speedup vs baseline: 16.2925x; 1.0447x over previous
//
#include <hip/hip_runtime.h>

// DCNv3 forward, FP32 I/O. N=8, H=W=64, C=256, G=16, GC=16, K=3, P=9. L=32768.
//
// Round-8:
//  - k_gemm stages A/Wh/Wl via __builtin_amdgcn_global_load_lds width=16
//    (single contiguous 24KB smem; 24 x 1KB wave-segments, 6/wave,
//    wave-uniform LDS base + lane*16). W buffers zero-padded at prep so
//    loads are unconditional.
//  - k_dwln also emits xb (bf16 cast of x, from its center tap) -> all GEMM
//    A-operands are plain bf16.
//  - head intermediate stored bf16 (halves gather HBM read).
// Dispatches: k_prep, k_dwln, gemm(in), gemm(head), k_gather, gemm(out).
// Fallback: round-3 minimal path (33.5 MB) if ws too small.

#define LL 32768
#define CC 256

typedef __bf16 bf16;
typedef __bf16 bf16x4 __attribute__((ext_vector_type(4)));
typedef __bf16 bf16x8 __attribute__((ext_vector_type(8)));
typedef float f32x4v __attribute__((ext_vector_type(4)));

__device__ __forceinline__ void gload16(const bf16* g, const bf16* lds_base) {
    __builtin_amdgcn_global_load_lds(
        (const __attribute__((address_space(1))) void*)g,
        (__attribute__((address_space(3))) void*)lds_base, 16, 0, 0);
}

// ---------------- weight prep: cvt + pack + pad, one launch ---------------
__global__ __launch_bounds__(256) void k_prep(
    const float* __restrict__ in_w, const float* __restrict__ off_w,
    const float* __restrict__ mask_w, const float* __restrict__ out_w,
    const float* __restrict__ dw_w, const float* __restrict__ off_b,
    const float* __restrict__ mask_b,
    bf16* __restrict__ in_h, bf16* __restrict__ in_l,
    bf16* __restrict__ hw_h, bf16* __restrict__ hw_l,
    bf16* __restrict__ out_h, bf16* __restrict__ out_l,
    float* __restrict__ dwT, float* __restrict__ hbias) {
    int idx = blockIdx.x * 256 + threadIdx.x;
    if (idx < 60416) {
        const float* s; bf16 *hi, *lo; int i;
        if (idx < 16384)      { s = in_w;   hi = in_h;          lo = in_l;          i = idx; }
        else if (idx < 34816) { s = off_w;  hi = hw_h;          lo = hw_l;          i = idx - 16384; }
        else if (idx < 44032) { s = mask_w; hi = hw_h + 73728;  lo = hw_l + 73728;  i = idx - 34816; }
        else                  { s = out_w;  hi = out_h;         lo = out_l;         i = idx - 44032; }
        float4 v = *(const float4*)(s + (size_t)i * 4);
        bf16x4 h, l;
        h[0] = (bf16)v.x; l[0] = (bf16)(v.x - (float)h[0]);
        h[1] = (bf16)v.y; l[1] = (bf16)(v.y - (float)h[1]);
        h[2] = (bf16)v.z; l[2] = (bf16)(v.z - (float)h[2]);
        h[3] = (bf16)v.w; l[3] = (bf16)(v.w - (float)h[3]);
        *(bf16x4*)(hi + (size_t)i * 4) = h;
        *(bf16x4*)(lo + (size_t)i * 4) = l;
    } else if (idx < 62720) {
        int e = idx - 60416;
        int c = e & 255, j = e >> 8;
        dwT[j * 256 + c] = dw_w[c * 9 + j];
    } else if (idx < 63232) {
        int e = idx - 62720;   // 0..511
        hbias[e] = (e < 288) ? off_b[e] : (e < 432 ? mask_b[e - 288] : 0.f);
    } else if (idx < 68352) {
        int e = idx - 63232;   // 0..5119 : zero-fill hw rows 432..511
        bf16x4 z = {(bf16)0.f, (bf16)0.f, (bf16)0.f, (bf16)0.f};
        *(bf16x4*)(hw_h + 110592 + (size_t)e * 4) = z;
        *(bf16x4*)(hw_l + 110592 + (size_t)e * 4) = z;
    }
}

// ------- dwconv3x3 + LN + GELU (wave/pixel); also emits xb = bf16(x) ------
__global__ __launch_bounds__(256) void k_dwln(
    const float* __restrict__ x, const float* __restrict__ dwT,
    const float* __restrict__ dw_b, const float* __restrict__ ln_g,
    const float* __restrict__ ln_b, bf16* __restrict__ x1h,
    bf16* __restrict__ xb) {
    int t = threadIdx.x;
    int q = t >> 6, u = t & 63;
    int l = blockIdx.x * 4 + q;
    int w = l & 63, h = (l >> 6) & 63, n = l >> 12;
    int c0 = u * 4;

    float4 acc = *(const float4*)(dw_b + c0);
    float4 xc = {0.f, 0.f, 0.f, 0.f};
#pragma unroll
    for (int kh = 0; kh < 3; ++kh) {
        int hh = h + kh - 1;
        if (hh < 0 || hh >= 64) continue;
#pragma unroll
        for (int kw = 0; kw < 3; ++kw) {
            int ww = w + kw - 1;
            if (ww < 0 || ww >= 64) continue;
            float4 xv = *(const float4*)(x + (size_t)(((n * 64 + hh) * 64) + ww) * CC + c0);
            if (kh == 1 && kw == 1) xc = xv;
            float4 wv = *(const float4*)(dwT + (kh * 3 + kw) * 256 + c0);
            acc.x += xv.x * wv.x; acc.y += xv.y * wv.y;
            acc.z += xv.z * wv.z; acc.w += xv.w * wv.w;
        }
    }
    bf16x4 xcb;
    xcb[0] = (bf16)xc.x; xcb[1] = (bf16)xc.y;
    xcb[2] = (bf16)xc.z; xcb[3] = (bf16)xc.w;
    *(bf16x4*)(xb + (size_t)l * CC + c0) = xcb;

    float s = acc.x + acc.y + acc.z + acc.w;
    float ss = acc.x * acc.x + acc.y * acc.y + acc.z * acc.z + acc.w * acc.w;
#pragma unroll
    for (int d = 1; d < 64; d <<= 1) {
        s += __shfl_xor(s, d);
        ss += __shfl_xor(ss, d);
    }
    float mean = s * (1.0f / 256.0f);
    float var = ss * (1.0f / 256.0f) - mean * mean;
    float rstd = rsqrtf(var + 1e-6f);
    float4 gv = *(const float4*)(ln_g + c0);
    float4 bv = *(const float4*)(ln_b + c0);
    float xn0 = (acc.x - mean) * rstd * gv.x + bv.x;
    float xn1 = (acc.y - mean) * rstd * gv.y + bv.y;
    float xn2 = (acc.z - mean) * rstd * gv.z + bv.z;
    float xn3 = (acc.w - mean) * rstd * gv.w + bv.w;
    bf16x4 oh;
    oh[0] = (bf16)(0.5f * xn0 * (1.0f + erff(xn0 * 0.70710678118654752f)));
    oh[1] = (bf16)(0.5f * xn1 * (1.0f + erff(xn1 * 0.70710678118654752f)));
    oh[2] = (bf16)(0.5f * xn2 * (1.0f + erff(xn2 * 0.70710678118654752f)));
    oh[3] = (bf16)(0.5f * xn3 * (1.0f + erff(xn3 * 0.70710678118654752f)));
    *(bf16x4*)(x1h + (size_t)l * CC + c0) = oh;
}

// ---- 128x128-tile 2-product split-bf16 MFMA GEMM, global_load_lds --------
// C = A@W^T + bias. A bf16 [M][256]; Wh/Wl bf16, rows >= grid coverage
// (zero-padded). K=256, BK=32. smem: A | Wh | Wl contiguous, 24 KB.
template <bool OBF16>
__global__ __launch_bounds__(256) void k_gemm(
    const bf16* __restrict__ A, const bf16* __restrict__ Wh,
    const bf16* __restrict__ Wl, const float* __restrict__ bias,
    float* __restrict__ C32, bf16* __restrict__ Cbf, int Nout) {
    int mb = blockIdx.x * 128, nb = blockIdx.y * 128;
    int t = threadIdx.x, wave = t >> 6, lane = t & 63;
    int wm = wave & 1, wn = wave >> 1;
    int fm = lane & 15, fq = lane >> 4;

    __shared__ bf16 smem[12288];   // [0,4096)=A  [4096,8192)=Wh  [8192,12288)=Wl

    // staging: 24 segments of 1 KB; wave w owns segs w*6..w*6+5.
    // seg -> arr = seg>>3 (0:A 1:Wh 2:Wl), rowbase=(seg&7)*16;
    // lane -> row = rowbase + lane/4, col = (lane&3)*8 (16B per lane).
    const bf16* gbase[6];
    const bf16* lbase[6];
#pragma unroll
    for (int j = 0; j < 6; ++j) {
        int seg = wave * 6 + j;
        int arr = seg >> 3;
        int row = (seg & 7) * 16 + (lane >> 2);
        int col = (lane & 3) * 8;
        const bf16* g = (arr == 0) ? (A + (size_t)(mb + row) * CC + col)
                      : (arr == 1) ? (Wh + (size_t)(nb + row) * CC + col)
                                   : (Wl + (size_t)(nb + row) * CC + col);
        gbase[j] = g;
        lbase[j] = smem + seg * 512;   // wave-uniform LDS base
    }

    f32x4v acc[4][4];
#pragma unroll
    for (int i = 0; i < 4; ++i)
#pragma unroll
        for (int j = 0; j < 4; ++j) acc[i][j] = (f32x4v){0.f, 0.f, 0.f, 0.f};

    for (int kc = 0; kc < 256; kc += 32) {
#pragma unroll
        for (int j = 0; j < 6; ++j) gload16(gbase[j] + kc, lbase[j]);
        __syncthreads();

        bf16x8 af[4], bfh[4], bfl[4];
#pragma unroll
        for (int i = 0; i < 4; ++i)
            af[i] = *(const bf16x8*)&smem[(wm * 64 + i * 16 + fm) * 32 + fq * 8];
#pragma unroll
        for (int j = 0; j < 4; ++j) {
            int br = wn * 64 + j * 16 + fm;
            bfh[j] = *(const bf16x8*)&smem[4096 + br * 32 + fq * 8];
            bfl[j] = *(const bf16x8*)&smem[8192 + br * 32 + fq * 8];
        }
#pragma unroll
        for (int i = 0; i < 4; ++i)
#pragma unroll
            for (int j = 0; j < 4; ++j) {
                acc[i][j] = __builtin_amdgcn_mfma_f32_16x16x32_bf16(
                    af[i], bfh[j], acc[i][j], 0, 0, 0);
                acc[i][j] = __builtin_amdgcn_mfma_f32_16x16x32_bf16(
                    af[i], bfl[j], acc[i][j], 0, 0, 0);
            }
        __syncthreads();
    }

    // D mapping: m = 16*tile + fq*4 + reg, n = 16*tile + fm
#pragma unroll
    for (int j = 0; j < 4; ++j) {
        int n_g = nb + wn * 64 + j * 16 + fm;
        if (n_g >= Nout) continue;
        float bv = bias[n_g];
#pragma unroll
        for (int i = 0; i < 4; ++i) {
            int m_g = mb + wm * 64 + i * 16 + fq * 4;
#pragma unroll
            for (int rg = 0; rg < 4; ++rg) {
                float o = acc[i][j][rg] + bv;
                if (OBF16)
                    Cbf[(size_t)(m_g + rg) * Nout + n_g] = (bf16)o;
                else
                    C32[(size_t)(m_g + rg) * Nout + n_g] = o;
            }
        }
    }
}

// ------ softmax + bilinear gather (8 ch/thread, bf16 xp + bf16 head) ------
__global__ __launch_bounds__(256) void k_gather(
    const bf16* __restrict__ xp, const bf16* __restrict__ head,
    bf16* __restrict__ rows) {
    int t = threadIdx.x;
    int q = t >> 5, u = t & 31;
    int l = blockIdx.x * 8 + q;
    int w = l & 63, h = (l >> 6) & 63, n = l >> 12;

    __shared__ float offs[8][288];
    __shared__ float ms[8][144];
    for (int j = u; j < 288; j += 32) offs[q][j] = (float)head[(size_t)l * 432 + j];
    for (int j = u; j < 144; j += 32) ms[q][j] = (float)head[(size_t)l * 432 + 288 + j];
    __syncthreads();

    if (u < 16) {
        int g = u;
        float mx = -1e30f;
#pragma unroll
        for (int p = 0; p < 9; ++p) mx = fmaxf(mx, ms[q][g * 9 + p]);
        float s = 0.f, e[9];
#pragma unroll
        for (int p = 0; p < 9; ++p) { e[p] = expf(ms[q][g * 9 + p] - mx); s += e[p]; }
        float inv = 1.0f / s;
#pragma unroll
        for (int p = 0; p < 9; ++p) ms[q][g * 9 + p] = e[p] * inv;
    }
    __syncthreads();

    int g = u >> 1;
    int c0 = g * 16 + (u & 1) * 8;
    const bf16* base = xp + (size_t)n * 4096 * CC + c0;
    float a0 = 0.f, a1 = 0.f, a2 = 0.f, a3 = 0.f;
    float a4 = 0.f, a5 = 0.f, a6 = 0.f, a7 = 0.f;
#pragma unroll
    for (int p = 0; p < 9; ++p) {
        float ox = offs[q][g * 18 + p * 2 + 0];
        float oy = offs[q][g * 18 + p * 2 + 1];
        float ax = (float)(w + (p / 3) - 1) + ox;
        float ay = (float)(h + (p % 3) - 1) + oy;
        float x0f = floorf(ax), y0f = floorf(ay);
        int x0 = (int)x0f, y0 = (int)y0f;
        float tx = ax - x0f, ty = ay - y0f;
        float m = ms[q][g * 9 + p];
        int idx[4]; float cw[4];
#pragma unroll
        for (int cr = 0; cr < 4; ++cr) {
            int xx = x0 + (cr & 1), yy = y0 + (cr >> 1);
            bool v = (xx >= 0) & (xx < 64) & (yy >= 0) & (yy < 64);
            int xc = min(max(xx, 0), 63), yc = min(max(yy, 0), 63);
            idx[cr] = (yc * 64 + xc) * CC;
            float wx = (cr & 1) ? tx : (1.f - tx);
            float wy = (cr >> 1) ? ty : (1.f - ty);
            cw[cr] = v ? (m * wx * wy) : 0.f;
        }
#pragma unroll
        for (int cr = 0; cr < 4; ++cr) {
            bf16x8 vb = *(const bf16x8*)(base + idx[cr]);
            float wt = cw[cr];
            a0 += wt * (float)vb[0]; a1 += wt * (float)vb[1];
            a2 += wt * (float)vb[2]; a3 += wt * (float)vb[3];
            a4 += wt * (float)vb[4]; a5 += wt * (float)vb[5];
            a6 += wt * (float)vb[6]; a7 += wt * (float)vb[7];
        }
    }
    bf16x8 oh;
    oh[0] = (bf16)a0; oh[1] = (bf16)a1; oh[2] = (bf16)a2; oh[3] = (bf16)a3;
    oh[4] = (bf16)a4; oh[5] = (bf16)a5; oh[6] = (bf16)a6; oh[7] = (bf16)a7;
    *(bf16x8*)(rows + (size_t)l * CC + c0) = oh;
}

// ======================= round-3 minimal fallback =========================
__device__ __forceinline__ float dot256f(const float* a, const float* wrow) {
    const float4* w4 = (const float4*)wrow;
    float s = 0.f;
#pragma unroll 16
    for (int i = 0; i < 64; ++i) {
        float4 u = w4[i];
        const float* ap = a + i * 4;
        s += ap[0] * u.x + ap[1] * u.y + ap[2] * u.z + ap[3] * u.w;
    }
    return s;
}

__global__ __launch_bounds__(256) void k_inproj_fb(
    const float* __restrict__ x, const float* __restrict__ in_w,
    const float* __restrict__ in_b, float* __restrict__ xp) {
    int l = blockIdx.x;
    int t = threadIdx.x;
    __shared__ float xa[256];
    xa[t] = x[l * CC + t];
    __syncthreads();
    xp[l * CC + t] = dot256f(xa, in_w + t * CC) + in_b[t];
}

__device__ __forceinline__ float fetch_px_fb(const float* base, int yy, int xx) {
    if (xx < 0 || xx >= 64 || yy < 0 || yy >= 64) return 0.f;
    return base[(yy * 64 + xx) * CC];
}

__global__ __launch_bounds__(256) void k_main_fb(
    const float* __restrict__ x, const float* __restrict__ xp,
    const float* __restrict__ dw_w, const float* __restrict__ dw_b,
    const float* __restrict__ ln_g, const float* __restrict__ ln_b,
    const float* __restrict__ off_w, const float* __restrict__ off_b,
    const float* __restrict__ mask_w, const float* __restrict__ mask_b,
    const float* __restrict__ out_w, const float* __restrict__ out_b,
    float* __restrict__ out) {
    int l = blockIdx.x;
    int t = threadIdx.x;
    int w = l & 63, h = (l >> 6) & 63, n = l >> 12;
    __shared__ float x1[256];
    __shared__ float red[256];
    __shared__ float offs[288];
    __shared__ float ms[144];
    __shared__ float row[256];

    float acc = dw_b[t];
#pragma unroll
    for (int kh = 0; kh < 3; ++kh) {
        int hh = h + kh - 1;
        if (hh < 0 || hh >= 64) continue;
#pragma unroll
        for (int kw = 0; kw < 3; ++kw) {
            int ww = w + kw - 1;
            if (ww < 0 || ww >= 64) continue;
            acc += x[(((n * 64 + hh) * 64) + ww) * CC + t] * dw_w[t * 9 + kh * 3 + kw];
        }
    }
    red[t] = acc;
    __syncthreads();
    for (int s = 128; s > 0; s >>= 1) {
        if (t < s) red[t] += red[t + s];
        __syncthreads();
    }
    float mean = red[0] * (1.0f / 256.0f);
    __syncthreads();
    float d = acc - mean;
    red[t] = d * d;
    __syncthreads();
    for (int s = 128; s > 0; s >>= 1) {
        if (t < s) red[t] += red[t + s];
        __syncthreads();
    }
    float var = red[0] * (1.0f / 256.0f);
    float xn = d * rsqrtf(var + 1e-6f) * ln_g[t] + ln_b[t];
    x1[t] = 0.5f * xn * (1.0f + erff(xn * 0.70710678118654752f));
    __syncthreads();

    offs[t] = dot256f(x1, off_w + t * CC) + off_b[t];
    if (t < 32) {
        int j = 256 + t;
        offs[j] = dot256f(x1, off_w + j * CC) + off_b[j];
    }
    if (t < 144) ms[t] = dot256f(x1, mask_w + t * CC) + mask_b[t];
    __syncthreads();

    if (t < 16) {
        int g = t;
        float mx = -1e30f;
#pragma unroll
        for (int p = 0; p < 9; ++p) mx = fmaxf(mx, ms[g * 9 + p]);
        float s = 0.f, e[9];
#pragma unroll
        for (int p = 0; p < 9; ++p) { e[p] = expf(ms[g * 9 + p] - mx); s += e[p]; }
        float inv = 1.0f / s;
#pragma unroll
        for (int p = 0; p < 9; ++p) ms[g * 9 + p] = e[p] * inv;
    }
    __syncthreads();

    int g = t >> 4;
    const float* base = xp + (size_t)n * 64 * 64 * CC + t;
    float acc2 = 0.f;
#pragma unroll
    for (int p = 0; p < 9; ++p) {
        float ox = offs[g * 18 + p * 2 + 0];
        float oy = offs[g * 18 + p * 2 + 1];
        float ax = (float)(w + (p / 3) - 1) + ox;
        float ay = (float)(h + (p % 3) - 1) + oy;
        float x0f = floorf(ax), y0f = floorf(ay);
        int x0 = (int)x0f, y0 = (int)y0f;
        float tx = ax - x0f, ty = ay - y0f;
        float v00 = fetch_px_fb(base, y0, x0);
        float v01 = fetch_px_fb(base, y0, x0 + 1);
        float v10 = fetch_px_fb(base, y0 + 1, x0);
        float v11 = fetch_px_fb(base, y0 + 1, x0 + 1);
        float bl = (v00 * (1.f - tx) + v01 * tx) * (1.f - ty) +
                   (v10 * (1.f - tx) + v11 * tx) * ty;
        acc2 += ms[g * 9 + p] * bl;
    }
    row[t] = acc2;
    __syncthreads();
    out[l * CC + t] = dot256f(row, out_w + t * CC) + out_b[t];
}

// ==========================================================================
extern "C" void kernel_launch(void* const* d_in, const int* in_sizes, int n_in,
                              void* d_out, int out_size, void* d_ws,
                              size_t ws_size, hipStream_t stream) {
    const float* x      = (const float*)d_in[0];
    const float* dw_w   = (const float*)d_in[1];
    const float* dw_b   = (const float*)d_in[2];
    const float* ln_g   = (const float*)d_in[3];
    const float* ln_b   = (const float*)d_in[4];
    const float* off_w  = (const float*)d_in[5];
    const float* off_b  = (const float*)d_in[6];
    const float* mask_w = (const float*)d_in[7];
    const float* mask_b = (const float*)d_in[8];
    const float* in_w   = (const float*)d_in[9];
    const float* in_b   = (const float*)d_in[10];
    const float* out_w  = (const float*)d_in[11];
    const float* out_b  = (const float*)d_in[12];
    float* out = (float*)d_out;

    const size_t szBF    = (size_t)LL * CC * 2;     // 16,777,216
    const size_t szHEADB = (size_t)LL * 432 * 2;    // 28,311,552
    const size_t szWB    = 1300480;                 // weight blob
    const size_t need    = 3 * szBF + szHEADB + szWB;  // ~80 MB

    dim3 blk(256);
    if (ws_size >= need) {
        char* p = (char*)d_ws;
        bf16* x1h = (bf16*)p; p += szBF;       // reused as rows after head GEMM
        bf16* xpb = (bf16*)p; p += szBF;
        bf16* xb  = (bf16*)p; p += szBF;
        bf16* headb = (bf16*)p; p += szHEADB;
        bf16* in_h  = (bf16*)p; p += 131072;
        bf16* in_l  = (bf16*)p; p += 131072;
        bf16* hw_h  = (bf16*)p; p += 262144;   // 512 x 256 bf16 (rows 432+ zeroed)
        bf16* hw_l  = (bf16*)p; p += 262144;
        bf16* out_h = (bf16*)p; p += 131072;
        bf16* out_l = (bf16*)p; p += 131072;
        float* dwT  = (float*)p; p += 9216;
        float* hbias = (float*)p;
        bf16* rows = x1h;

        k_prep<<<dim3(267), blk, 0, stream>>>(in_w, off_w, mask_w, out_w, dw_w,
                                              off_b, mask_b, in_h, in_l, hw_h,
                                              hw_l, out_h, out_l, dwT, hbias);
        k_dwln<<<dim3(LL / 4), blk, 0, stream>>>(x, dwT, dw_b, ln_g, ln_b, x1h, xb);
        k_gemm<true><<<dim3(256, 2), blk, 0, stream>>>(
            xb, in_h, in_l, in_b, nullptr, xpb, 256);
        k_gemm<true><<<dim3(256, 4), blk, 0, stream>>>(
            x1h, hw_h, hw_l, hbias, nullptr, headb, 432);
        k_gather<<<dim3(LL / 8), blk, 0, stream>>>(xpb, headb, rows);
        k_gemm<false><<<dim3(256, 2), blk, 0, stream>>>(
            rows, out_h, out_l, out_b, out, nullptr, 256);
    } else {
        float* xp = (float*)d_ws;   // 33.5 MB
        k_inproj_fb<<<dim3(LL), blk, 0, stream>>>(x, in_w, in_b, xp);
        k_main_fb<<<dim3(LL), blk, 0, stream>>>(x, xp, dw_w, dw_b, ln_g, ln_b,
                                                off_w, off_b, mask_w, mask_b,
                                                out_w, out_b, out);
    }
}